// Round 1
// baseline (1206.669 us; speedup 1.0000x reference)
//
#include <hip/hip_runtime.h>
#include <cstddef>

#define SB 4
#define SS 2048
#define SH 1024
#define NH 16
#define HD 64
#define WIN 256

// C[M,N] = A[M,K] @ W[N,K]^T (+ bias). 128x128 tile, BK=16, 256 thr, 8x8/thread.
__global__ __launch_bounds__(256) void gemm_abt(
    const float* __restrict__ A, const float* __restrict__ W,
    const float* __restrict__ bias, float* __restrict__ C,
    int M, int N, int K, int has_bias)
{
    // +4 pad keeps rows 16B-aligned (132*4=528=33*16) and breaks store conflicts
    __shared__ __align__(16) float As[16][132];
    __shared__ __align__(16) float Bs[16][132];
    const int tid = threadIdx.x;
    const int m0 = blockIdx.x * 128;
    const int n0 = blockIdx.y * 128;
    const int tx = tid & 15;
    const int ty = tid >> 4;

    float acc[8][8];
#pragma unroll
    for (int i = 0; i < 8; ++i)
#pragma unroll
        for (int j = 0; j < 8; ++j) acc[i][j] = 0.f;

    for (int k0 = 0; k0 < K; k0 += 16) {
        __syncthreads();
#pragma unroll
        for (int u = 0; u < 2; ++u) {
            int f = tid * 2 + u;      // 0..511 float4 slots, 128 rows x 4
            int row = f >> 2;
            int c4 = f & 3;
            float4 av = *(const float4*)(A + (size_t)(m0 + row) * K + k0 + c4 * 4);
            As[c4 * 4 + 0][row] = av.x;
            As[c4 * 4 + 1][row] = av.y;
            As[c4 * 4 + 2][row] = av.z;
            As[c4 * 4 + 3][row] = av.w;
            float4 bv = *(const float4*)(W + (size_t)(n0 + row) * K + k0 + c4 * 4);
            Bs[c4 * 4 + 0][row] = bv.x;
            Bs[c4 * 4 + 1][row] = bv.y;
            Bs[c4 * 4 + 2][row] = bv.z;
            Bs[c4 * 4 + 3][row] = bv.w;
        }
        __syncthreads();
#pragma unroll
        for (int kk = 0; kk < 16; ++kk) {
            float a[8], b[8];
#pragma unroll
            for (int i = 0; i < 8; ++i) a[i] = As[kk][ty * 8 + i];
#pragma unroll
            for (int j = 0; j < 8; ++j) b[j] = Bs[kk][tx * 8 + j];
#pragma unroll
            for (int i = 0; i < 8; ++i)
#pragma unroll
                for (int j = 0; j < 8; ++j)
                    acc[i][j] = fmaf(a[i], b[j], acc[i][j]);
        }
    }

#pragma unroll
    for (int i = 0; i < 8; ++i) {
        int m = m0 + ty * 8 + i;
#pragma unroll
        for (int j4 = 0; j4 < 2; ++j4) {
            int n = n0 + tx * 8 + j4 * 4;
            float4 o;
            o.x = acc[i][j4 * 4 + 0];
            o.y = acc[i][j4 * 4 + 1];
            o.z = acc[i][j4 * 4 + 2];
            o.w = acc[i][j4 * 4 + 3];
            if (has_bias) {
                o.x += bias[n + 0];
                o.y += bias[n + 1];
                o.z += bias[n + 2];
                o.w += bias[n + 3];
            }
            *(float4*)(C + (size_t)m * N + n) = o;
        }
    }
}

// Windowed causal attention, one thread per query row, 128 queries/workgroup.
// Scores are unscaled (per reference). No online-max: |s| <~ 60 << 88 so raw
// exp(s) cannot overflow fp32; this halves the PV inner-loop cost.
// ctx may alias Q: each thread reads only its own q row (fully, at start) and
// writes only that same row (at end) -> race-free. No __restrict__ on Q/ctx.
__global__ __launch_bounds__(128) void attn_local(
    const float* Q, const float* __restrict__ Kg,
    const float* __restrict__ Vg, const float* __restrict__ amask,
    float* ctx)
{
    __shared__ __align__(16) float Ks[64][64];
    __shared__ __align__(16) float Vs[64][64];
    const int wid = blockIdx.x;       // B*NH*(SS/128) = 1024
    const int qb = wid & 15;          // SS/128 = 16
    const int h = (wid >> 4) & 15;
    const int b = wid >> 8;
    const int t0 = qb * 128;
    const int tid = threadIdx.x;
    const int i = t0 + tid;           // this thread's query row

    const size_t rowbase = ((size_t)(b * SS + i) * SH) + h * HD;
    float q[64], acc[64];
#pragma unroll
    for (int d4 = 0; d4 < 16; ++d4) {
        float4 t = *(const float4*)(Q + rowbase + d4 * 4);
        q[d4 * 4 + 0] = t.x; q[d4 * 4 + 1] = t.y;
        q[d4 * 4 + 2] = t.z; q[d4 * 4 + 3] = t.w;
    }
#pragma unroll
    for (int d = 0; d < 64; ++d) acc[d] = 0.f;
    float l = 0.f;

    int c_lo = t0 - (WIN - 1);
    c_lo = (c_lo < 0) ? 0 : (c_lo >> 6);
    const int c_hi = (t0 >> 6) + 1;

    for (int c = c_lo; c <= c_hi; ++c) {
        const size_t cb = ((size_t)(b * SS + c * 64) * SH) + h * HD;
        __syncthreads();
#pragma unroll
        for (int it = 0; it < 8; ++it) {
            int idx = tid + 128 * it;   // 1024 float4 per 64x64 tile
            int row = idx >> 4;
            int col = idx & 15;
            *(float4*)&Ks[row][col * 4] =
                *(const float4*)(Kg + cb + (size_t)row * SH + col * 4);
            *(float4*)&Vs[row][col * 4] =
                *(const float4*)(Vg + cb + (size_t)row * SH + col * 4);
        }
        __syncthreads();

        int lo = i - (WIN - 1) - c * 64;   // valid keys: lo <= jj <= hi
        int hi = i - c * 64;
        lo = lo < 0 ? 0 : lo;
        hi = hi > 63 ? 63 : hi;
        for (int jj = 0; jj < 64; ++jj) {
            if (jj < lo || jj > hi) continue;
            float s0 = 0.f, s1 = 0.f, s2 = 0.f, s3 = 0.f;
#pragma unroll
            for (int d4 = 0; d4 < 16; ++d4) {
                float4 kv = *(const float4*)&Ks[jj][d4 * 4];   // wave broadcast
                s0 = fmaf(q[d4 * 4 + 0], kv.x, s0);
                s1 = fmaf(q[d4 * 4 + 1], kv.y, s1);
                s2 = fmaf(q[d4 * 4 + 2], kv.z, s2);
                s3 = fmaf(q[d4 * 4 + 3], kv.w, s3);
            }
            float p = __expf((s0 + s1) + (s2 + s3));
            l += p;
#pragma unroll
            for (int d4 = 0; d4 < 16; ++d4) {
                float4 vv = *(const float4*)&Vs[jj][d4 * 4];   // wave broadcast
                acc[d4 * 4 + 0] = fmaf(p, vv.x, acc[d4 * 4 + 0]);
                acc[d4 * 4 + 1] = fmaf(p, vv.y, acc[d4 * 4 + 1]);
                acc[d4 * 4 + 2] = fmaf(p, vv.z, acc[d4 * 4 + 2]);
                acc[d4 * 4 + 3] = fmaf(p, vv.w, acc[d4 * 4 + 3]);
            }
        }
    }

    const float inv = 1.0f / l;
#pragma unroll
    for (int d4 = 0; d4 < 16; ++d4) {
        float4 m4 = *(const float4*)(amask + rowbase + d4 * 4);
        float4 o;
        o.x = acc[d4 * 4 + 0] * inv * m4.x;
        o.y = acc[d4 * 4 + 1] * inv * m4.y;
        o.z = acc[d4 * 4 + 2] * inv * m4.z;
        o.w = acc[d4 * 4 + 3] * inv * m4.w;
        *(float4*)(ctx + rowbase + d4 * 4) = o;
    }
}

extern "C" void kernel_launch(void* const* d_in, const int* in_sizes, int n_in,
                              void* d_out, int out_size, void* d_ws, size_t ws_size,
                              hipStream_t stream)
{
    const float* x     = (const float*)d_in[0];
    const float* xc    = (const float*)d_in[1];
    const float* amask = (const float*)d_in[2];
    const float* Wq    = (const float*)d_in[3];
    const float* Wk    = (const float*)d_in[4];
    const float* Wv    = (const float*)d_in[5];
    const float* Wo    = (const float*)d_in[6];
    const float* bo    = (const float*)d_in[7];
    float* out = (float*)d_out;

    const int M = SB * SS;                     // 8192
    float* Qb = (float*)d_ws;                  // 32MB, reused as ctx buffer
    float* Kb = Qb + (size_t)M * SH;           // 32MB
    float* Vb = Kb + (size_t)M * SH;           // 32MB  (total 96MB of ws)

    dim3 gg(M / 128, SH / 128);
    dim3 gb(256);
    hipLaunchKernelGGL(gemm_abt, gg, gb, 0, stream, x,  Wq, (const float*)nullptr, Qb, M, SH, SH, 0);
    hipLaunchKernelGGL(gemm_abt, gg, gb, 0, stream, xc, Wk, (const float*)nullptr, Kb, M, SH, SH, 0);
    hipLaunchKernelGGL(gemm_abt, gg, gb, 0, stream, xc, Wv, (const float*)nullptr, Vb, M, SH, SH, 0);

    hipLaunchKernelGGL(attn_local, dim3(SB * NH * (SS / 128)), dim3(128), 0, stream,
                       Qb, Kb, Vb, amask, Qb);

    hipLaunchKernelGGL(gemm_abt, gg, gb, 0, stream, Qb, Wo, bo, out, M, SH, SH, 1);
}

// Round 2
// 622.008 us; speedup vs baseline: 1.9400x; 1.9400x over previous
//
#include <hip/hip_runtime.h>
#include <hip/hip_bf16.h>
#include <cstddef>

#define SB 4
#define SS 2048
#define SH 1024
#define NH 16
#define HD 64
#define WIN 256

typedef __attribute__((ext_vector_type(8))) short bf16x8;
typedef __attribute__((ext_vector_type(4))) float f32x4;

static __device__ __forceinline__ ushort2 pk_bf16(float a, float b) {
    __hip_bfloat162 h = __float22bfloat162_rn(make_float2(a, b));
    union { __hip_bfloat162 h2; ushort2 u2; } u;
    u.h2 = h;
    return u.u2;
}
static __device__ __forceinline__ float bf_hi_f(unsigned short h) {
    return __uint_as_float(((unsigned)h) << 16);
}

// C[M,N] = A[M,K] @ W[N,K]^T (+ bias). fp32 in/out, bf16 MFMA inside.
// SPLIT=1: bf16x3 error-compensated (hi*hi + hi*lo + lo*hi) ~ fp16+ accuracy.
// SPLIT=0: plain bf16 (hi only).
// 128x128 tile, BK=32, 256 thr = 4 waves, wave computes 64x64 via 4x4 MFMAs.
template<int SPLIT>
__global__ __launch_bounds__(256) void gemm_mfma(
    const float* __restrict__ A, const float* __restrict__ W,
    const float* __restrict__ bias, float* __restrict__ C,
    int M, int N, int K, int has_bias)
{
    // [row][k] bf16, row stride 32 elems (64B). Fragment reads are 16B/lane,
    // wave covers a contiguous 1KB block -> conflict-light.
    __shared__ unsigned short Ah[128 * 32];
    __shared__ unsigned short Bh[128 * 32];
    __shared__ unsigned short Al[SPLIT ? 128 * 32 : 4];
    __shared__ unsigned short Bl[SPLIT ? 128 * 32 : 4];

    const int tid = threadIdx.x;
    const int m0 = blockIdx.x * 128;
    const int n0 = blockIdx.y * 128;
    const int wave = tid >> 6;
    const int lane = tid & 63;
    const int wm = (wave & 1) * 64;   // wave's m offset within tile
    const int wn = (wave >> 1) * 64;  // wave's n offset within tile
    const int lrow = lane & 15;
    const int lk8 = (lane >> 4) * 8;

    f32x4 acc[4][4];
#pragma unroll
    for (int i = 0; i < 4; ++i)
#pragma unroll
        for (int j = 0; j < 4; ++j)
            acc[i][j] = (f32x4){0.f, 0.f, 0.f, 0.f};

    for (int k0 = 0; k0 < K; k0 += 32) {
        __syncthreads();
        // Stage A and W tiles: 128 rows x 32 k fp32 -> bf16 (hi [+lo]).
        // 1024 float4 per tile, 4 per thread.
#pragma unroll
        for (int u = 0; u < 4; ++u) {
            int f = u * 256 + tid;
            int row = f >> 3;
            int kc = (f & 7) * 4;
            int lidx = row * 32 + kc;

            float4 av = *(const float4*)(A + (size_t)(m0 + row) * K + k0 + kc);
            ushort2 ah01 = pk_bf16(av.x, av.y);
            ushort2 ah23 = pk_bf16(av.z, av.w);
            *(ushort4*)&Ah[lidx] = make_ushort4(ah01.x, ah01.y, ah23.x, ah23.y);
            if (SPLIT) {
                ushort2 al01 = pk_bf16(av.x - bf_hi_f(ah01.x), av.y - bf_hi_f(ah01.y));
                ushort2 al23 = pk_bf16(av.z - bf_hi_f(ah23.x), av.w - bf_hi_f(ah23.y));
                *(ushort4*)&Al[lidx] = make_ushort4(al01.x, al01.y, al23.x, al23.y);
            }

            float4 bv = *(const float4*)(W + (size_t)(n0 + row) * K + k0 + kc);
            ushort2 bh01 = pk_bf16(bv.x, bv.y);
            ushort2 bh23 = pk_bf16(bv.z, bv.w);
            *(ushort4*)&Bh[lidx] = make_ushort4(bh01.x, bh01.y, bh23.x, bh23.y);
            if (SPLIT) {
                ushort2 bl01 = pk_bf16(bv.x - bf_hi_f(bh01.x), bv.y - bf_hi_f(bh01.y));
                ushort2 bl23 = pk_bf16(bv.z - bf_hi_f(bh23.x), bv.w - bf_hi_f(bh23.y));
                *(ushort4*)&Bl[lidx] = make_ushort4(bl01.x, bl01.y, bl23.x, bl23.y);
            }
        }
        __syncthreads();

        // Fragment reads + MFMA. A-frag: lane holds A[m=lane&15][k=(lane>>4)*8+j];
        // B-frag mirrors with n=lane&15 (W stored row-major [n][k] like A).
        bf16x8 bhi[4], blo[4];
#pragma unroll
        for (int j = 0; j < 4; ++j) {
            int off = (wn + j * 16 + lrow) * 32 + lk8;
            bhi[j] = *(const bf16x8*)&Bh[off];
            if (SPLIT) blo[j] = *(const bf16x8*)&Bl[off];
        }
#pragma unroll
        for (int i = 0; i < 4; ++i) {
            int off = (wm + i * 16 + lrow) * 32 + lk8;
            bf16x8 ahi = *(const bf16x8*)&Ah[off];
            bf16x8 alo;
            if (SPLIT) alo = *(const bf16x8*)&Al[off];
#pragma unroll
            for (int j = 0; j < 4; ++j) {
                acc[i][j] = __builtin_amdgcn_mfma_f32_16x16x32_bf16(ahi, bhi[j], acc[i][j], 0, 0, 0);
                if (SPLIT) {
                    acc[i][j] = __builtin_amdgcn_mfma_f32_16x16x32_bf16(ahi, blo[j], acc[i][j], 0, 0, 0);
                    acc[i][j] = __builtin_amdgcn_mfma_f32_16x16x32_bf16(alo, bhi[j], acc[i][j], 0, 0, 0);
                }
            }
        }
    }

    // Epilogue. C/D layout: col=lane&15, row=(lane>>4)*4+reg.
#pragma unroll
    for (int i = 0; i < 4; ++i) {
        int rbase = m0 + wm + i * 16 + (lane >> 4) * 4;
#pragma unroll
        for (int j = 0; j < 4; ++j) {
            int col = n0 + wn + j * 16 + (lane & 15);
            float badd = has_bias ? bias[col] : 0.f;
#pragma unroll
            for (int r = 0; r < 4; ++r)
                C[(size_t)(rbase + r) * N + col] = acc[i][j][r] + badd;
        }
    }
}

// Windowed causal attention, one thread per query row, 128 queries/workgroup.
// Scores unscaled (per reference). No online-max: |s| <~ 60 << 88 so raw
// exp(s) cannot overflow fp32. ctx aliases Q: each thread reads only its own
// q row (fully, at start) and writes only that row (at end) -> race-free.
__global__ __launch_bounds__(128) void attn_local(
    const float* Q, const float* __restrict__ Kg,
    const float* __restrict__ Vg, const float* __restrict__ amask,
    float* ctx)
{
    __shared__ __align__(16) float Ks[64][64];
    __shared__ __align__(16) float Vs[64][64];
    const int wid = blockIdx.x;       // B*NH*(SS/128) = 1024
    const int qb = wid & 15;
    const int h = (wid >> 4) & 15;
    const int b = wid >> 8;
    const int t0 = qb * 128;
    const int tid = threadIdx.x;
    const int i = t0 + tid;

    const size_t rowbase = ((size_t)(b * SS + i) * SH) + h * HD;
    float q[64], acc[64];
#pragma unroll
    for (int d4 = 0; d4 < 16; ++d4) {
        float4 t = *(const float4*)(Q + rowbase + d4 * 4);
        q[d4 * 4 + 0] = t.x; q[d4 * 4 + 1] = t.y;
        q[d4 * 4 + 2] = t.z; q[d4 * 4 + 3] = t.w;
    }
#pragma unroll
    for (int d = 0; d < 64; ++d) acc[d] = 0.f;
    float l = 0.f;

    int c_lo = t0 - (WIN - 1);
    c_lo = (c_lo < 0) ? 0 : (c_lo >> 6);
    const int c_hi = (t0 >> 6) + 1;

    for (int c = c_lo; c <= c_hi; ++c) {
        const size_t cb = ((size_t)(b * SS + c * 64) * SH) + h * HD;
        __syncthreads();
#pragma unroll
        for (int it = 0; it < 8; ++it) {
            int idx = tid + 128 * it;
            int row = idx >> 4;
            int col = idx & 15;
            *(float4*)&Ks[row][col * 4] =
                *(const float4*)(Kg + cb + (size_t)row * SH + col * 4);
            *(float4*)&Vs[row][col * 4] =
                *(const float4*)(Vg + cb + (size_t)row * SH + col * 4);
        }
        __syncthreads();

        int lo = i - (WIN - 1) - c * 64;
        int hi = i - c * 64;
        lo = lo < 0 ? 0 : lo;
        hi = hi > 63 ? 63 : hi;
        for (int jj = 0; jj < 64; ++jj) {
            if (jj < lo || jj > hi) continue;
            float s0 = 0.f, s1 = 0.f, s2 = 0.f, s3 = 0.f;
#pragma unroll
            for (int d4 = 0; d4 < 16; ++d4) {
                float4 kv = *(const float4*)&Ks[jj][d4 * 4];
                s0 = fmaf(q[d4 * 4 + 0], kv.x, s0);
                s1 = fmaf(q[d4 * 4 + 1], kv.y, s1);
                s2 = fmaf(q[d4 * 4 + 2], kv.z, s2);
                s3 = fmaf(q[d4 * 4 + 3], kv.w, s3);
            }
            float p = __expf((s0 + s1) + (s2 + s3));
            l += p;
#pragma unroll
            for (int d4 = 0; d4 < 16; ++d4) {
                float4 vv = *(const float4*)&Vs[jj][d4 * 4];
                acc[d4 * 4 + 0] = fmaf(p, vv.x, acc[d4 * 4 + 0]);
                acc[d4 * 4 + 1] = fmaf(p, vv.y, acc[d4 * 4 + 1]);
                acc[d4 * 4 + 2] = fmaf(p, vv.z, acc[d4 * 4 + 2]);
                acc[d4 * 4 + 3] = fmaf(p, vv.w, acc[d4 * 4 + 3]);
            }
        }
    }

    const float inv = 1.0f / l;
#pragma unroll
    for (int d4 = 0; d4 < 16; ++d4) {
        float4 m4 = *(const float4*)(amask + rowbase + d4 * 4);
        float4 o;
        o.x = acc[d4 * 4 + 0] * inv * m4.x;
        o.y = acc[d4 * 4 + 1] * inv * m4.y;
        o.z = acc[d4 * 4 + 2] * inv * m4.z;
        o.w = acc[d4 * 4 + 3] * inv * m4.w;
        *(float4*)(ctx + rowbase + d4 * 4) = o;
    }
}

extern "C" void kernel_launch(void* const* d_in, const int* in_sizes, int n_in,
                              void* d_out, int out_size, void* d_ws, size_t ws_size,
                              hipStream_t stream)
{
    const float* x     = (const float*)d_in[0];
    const float* xc    = (const float*)d_in[1];
    const float* amask = (const float*)d_in[2];
    const float* Wq    = (const float*)d_in[3];
    const float* Wk    = (const float*)d_in[4];
    const float* Wv    = (const float*)d_in[5];
    const float* Wo    = (const float*)d_in[6];
    const float* bo    = (const float*)d_in[7];
    float* out = (float*)d_out;

    const int M = SB * SS;                     // 8192
    float* Qb = (float*)d_ws;                  // 32MB, reused as ctx buffer
    float* Kb = Qb + (size_t)M * SH;           // 32MB
    float* Vb = Kb + (size_t)M * SH;           // 32MB  (total 96MB of ws)

    dim3 gg(M / 128, SH / 128);
    dim3 gb(256);
    // Q,K: bf16x3 (score accuracy is exp-amplified); V,O: plain bf16.
    hipLaunchKernelGGL((gemm_mfma<1>), gg, gb, 0, stream, x,  Wq, bo, Qb, M, SH, SH, 0);
    hipLaunchKernelGGL((gemm_mfma<1>), gg, gb, 0, stream, xc, Wk, bo, Kb, M, SH, SH, 0);
    hipLaunchKernelGGL((gemm_mfma<0>), gg, gb, 0, stream, xc, Wv, bo, Vb, M, SH, SH, 0);

    hipLaunchKernelGGL(attn_local, dim3(SB * NH * (SS / 128)), dim3(128), 0, stream,
                       Qb, Kb, Vb, amask, Qb);

    hipLaunchKernelGGL((gemm_mfma<0>), gg, gb, 0, stream, Qb, Wo, bo, out, M, SH, SH, 1);
}

// Round 3
// 413.041 us; speedup vs baseline: 2.9214x; 1.5059x over previous
//
#include <hip/hip_runtime.h>
#include <hip/hip_bf16.h>
#include <cstddef>

#define SB 4
#define SS 2048
#define SH 1024
#define NH 16
#define HD 64
#define WIN 256

typedef __attribute__((ext_vector_type(8))) short bf16x8;
typedef __attribute__((ext_vector_type(4))) float f32x4;

static __device__ __forceinline__ ushort2 pk_bf16(float a, float b) {
    __hip_bfloat162 h = __float22bfloat162_rn(make_float2(a, b));
    union { __hip_bfloat162 h2; ushort2 u2; } u;
    u.h2 = h;
    return u.u2;
}
static __device__ __forceinline__ float bf_hi_f(unsigned short h) {
    return __uint_as_float(((unsigned)h) << 16);
}

// C[M,N] = A[M,K] @ W[N,K]^T. 128x128 tile, BK=32, 4 waves, 4x4 16x16x32 MFMAs.
// SPLIT: bf16x3 error-compensated A/W (hi*hi + hi*lo + lo*hi).
// ABF:   A is bf16 (ushort) instead of fp32 (no cvt staging for A).
// OUTM:  0 = fp32 + bias -> C1(float*)
//        1 = hi/lo bf16  -> C1,C2 (ushort*)          [for Q,K]
//        2 = transposed bf16 C^T[n][m] -> C1(ushort*) [for V]
template<int SPLIT, int ABF, int OUTM>
__global__ __launch_bounds__(256) void gemm_mfma(
    const void* __restrict__ Ap, const float* __restrict__ W,
    const float* __restrict__ bias, void* __restrict__ C1v,
    void* __restrict__ C2v, int M, int N, int K)
{
    __shared__ __align__(16) unsigned short Ah[128 * 32];
    __shared__ __align__(16) unsigned short Bh[128 * 32];
    __shared__ __align__(16) unsigned short Al[SPLIT ? 128 * 32 : 8];
    __shared__ __align__(16) unsigned short Bl[SPLIT ? 128 * 32 : 8];

    const int tid = threadIdx.x;
    const int m0 = blockIdx.x * 128;
    const int n0 = blockIdx.y * 128;
    const int wave = tid >> 6;
    const int lane = tid & 63;
    const int wm = (wave & 1) * 64;
    const int wn = (wave >> 1) * 64;
    const int lrow = lane & 15;
    const int lk8 = (lane >> 4) * 8;

    f32x4 acc[4][4];
#pragma unroll
    for (int i = 0; i < 4; ++i)
#pragma unroll
        for (int j = 0; j < 4; ++j)
            acc[i][j] = (f32x4){0.f, 0.f, 0.f, 0.f};

    for (int k0 = 0; k0 < K; k0 += 32) {
        __syncthreads();
        if (ABF) {
            const unsigned short* Ab = (const unsigned short*)Ap;
#pragma unroll
            for (int u = 0; u < 2; ++u) {
                int slot = u * 256 + tid;        // 512 ushort8 slots
                int row = slot >> 2;
                int k8 = (slot & 3) * 8;
                *(uint4*)&Ah[row * 32 + k8] =
                    *(const uint4*)(Ab + (size_t)(m0 + row) * K + k0 + k8);
            }
#pragma unroll
            for (int u = 0; u < 4; ++u) {
                int f = u * 256 + tid;
                int row = f >> 3;
                int kc = (f & 7) * 4;
                float4 bv = *(const float4*)(W + (size_t)(n0 + row) * K + k0 + kc);
                ushort2 b01 = pk_bf16(bv.x, bv.y);
                ushort2 b23 = pk_bf16(bv.z, bv.w);
                *(ushort4*)&Bh[row * 32 + kc] = make_ushort4(b01.x, b01.y, b23.x, b23.y);
            }
        } else {
            const float* Af = (const float*)Ap;
#pragma unroll
            for (int u = 0; u < 4; ++u) {
                int f = u * 256 + tid;
                int row = f >> 3;
                int kc = (f & 7) * 4;
                int lidx = row * 32 + kc;

                float4 av = *(const float4*)(Af + (size_t)(m0 + row) * K + k0 + kc);
                ushort2 ah01 = pk_bf16(av.x, av.y);
                ushort2 ah23 = pk_bf16(av.z, av.w);
                *(ushort4*)&Ah[lidx] = make_ushort4(ah01.x, ah01.y, ah23.x, ah23.y);
                if (SPLIT) {
                    ushort2 al01 = pk_bf16(av.x - bf_hi_f(ah01.x), av.y - bf_hi_f(ah01.y));
                    ushort2 al23 = pk_bf16(av.z - bf_hi_f(ah23.x), av.w - bf_hi_f(ah23.y));
                    *(ushort4*)&Al[lidx] = make_ushort4(al01.x, al01.y, al23.x, al23.y);
                }
                float4 bv = *(const float4*)(W + (size_t)(n0 + row) * K + k0 + kc);
                ushort2 bh01 = pk_bf16(bv.x, bv.y);
                ushort2 bh23 = pk_bf16(bv.z, bv.w);
                *(ushort4*)&Bh[lidx] = make_ushort4(bh01.x, bh01.y, bh23.x, bh23.y);
                if (SPLIT) {
                    ushort2 bl01 = pk_bf16(bv.x - bf_hi_f(bh01.x), bv.y - bf_hi_f(bh01.y));
                    ushort2 bl23 = pk_bf16(bv.z - bf_hi_f(bh23.x), bv.w - bf_hi_f(bh23.y));
                    *(ushort4*)&Bl[lidx] = make_ushort4(bl01.x, bl01.y, bl23.x, bl23.y);
                }
            }
        }
        __syncthreads();

        bf16x8 bhi[4], blo[4];
#pragma unroll
        for (int j = 0; j < 4; ++j) {
            int off = (wn + j * 16 + lrow) * 32 + lk8;
            bhi[j] = *(const bf16x8*)&Bh[off];
            if (SPLIT) blo[j] = *(const bf16x8*)&Bl[off];
        }
#pragma unroll
        for (int i = 0; i < 4; ++i) {
            int off = (wm + i * 16 + lrow) * 32 + lk8;
            bf16x8 ahi = *(const bf16x8*)&Ah[off];
            bf16x8 alo;
            if (SPLIT) alo = *(const bf16x8*)&Al[off];
#pragma unroll
            for (int j = 0; j < 4; ++j) {
                acc[i][j] = __builtin_amdgcn_mfma_f32_16x16x32_bf16(ahi, bhi[j], acc[i][j], 0, 0, 0);
                if (SPLIT) {
                    acc[i][j] = __builtin_amdgcn_mfma_f32_16x16x32_bf16(ahi, blo[j], acc[i][j], 0, 0, 0);
                    acc[i][j] = __builtin_amdgcn_mfma_f32_16x16x32_bf16(alo, bhi[j], acc[i][j], 0, 0, 0);
                }
            }
        }
    }

    // C/D layout: col = lane&15, row = (lane>>4)*4 + reg.
    if (OUTM == 0) {
        float* C = (float*)C1v;
#pragma unroll
        for (int i = 0; i < 4; ++i) {
            int rbase = m0 + wm + i * 16 + (lane >> 4) * 4;
#pragma unroll
            for (int j = 0; j < 4; ++j) {
                int col = n0 + wn + j * 16 + (lane & 15);
                float badd = bias[col];
#pragma unroll
                for (int r = 0; r < 4; ++r)
                    C[(size_t)(rbase + r) * N + col] = acc[i][j][r] + badd;
            }
        }
    } else if (OUTM == 1) {
        unsigned short* Ch = (unsigned short*)C1v;
        unsigned short* Cl = (unsigned short*)C2v;
#pragma unroll
        for (int i = 0; i < 4; ++i) {
            int rbase = m0 + wm + i * 16 + (lane >> 4) * 4;
#pragma unroll
            for (int j = 0; j < 4; ++j) {
                int col = n0 + wn + j * 16 + (lane & 15);
#pragma unroll
                for (int r = 0; r < 4; ++r) {
                    float v = acc[i][j][r];
                    unsigned short hi = pk_bf16(v, 0.f).x;
                    Ch[(size_t)(rbase + r) * N + col] = hi;
                    Cl[(size_t)(rbase + r) * N + col] = pk_bf16(v - bf_hi_f(hi), 0.f).x;
                }
            }
        }
    } else {
        unsigned short* Ct = (unsigned short*)C1v;   // C^T[n][m], row stride M
#pragma unroll
        for (int i = 0; i < 4; ++i) {
            int mb = m0 + wm + i * 16 + (lane >> 4) * 4;
#pragma unroll
            for (int j = 0; j < 4; ++j) {
                int col = n0 + wn + j * 16 + (lane & 15);
                ushort4 w4 = make_ushort4(
                    pk_bf16(acc[i][j][0], 0.f).x, pk_bf16(acc[i][j][1], 0.f).x,
                    pk_bf16(acc[i][j][2], 0.f).x, pk_bf16(acc[i][j][3], 0.f).x);
                *(ushort4*)(Ct + (size_t)col * M + mb) = w4;
            }
        }
    }
}

// MFMA flash attention over the local causal window.
// Block = 256 thr = 4 waves; 128 queries of one (b,h); K-chunks of 64.
// S via bf16x3 split (exp-amplified accuracy), P@V in plain bf16.
// P (bf16, A-layout) overlays the K hi/lo LDS after S is consumed.
__global__ __launch_bounds__(256) void attn_mfma(
    const unsigned short* __restrict__ Qhig, const unsigned short* __restrict__ Qlog,
    const unsigned short* __restrict__ Khig, const unsigned short* __restrict__ Klog,
    const unsigned short* __restrict__ Vtg,  const float* __restrict__ amask,
    unsigned short* __restrict__ ctxg)
{
    __shared__ __align__(16) unsigned short Qhi_s[128 * 72];
    __shared__ __align__(16) unsigned short Qlo_s[128 * 72];
    __shared__ __align__(16) unsigned short K_s[2 * 64 * 72];  // hi|lo, P overlays
    __shared__ __align__(16) unsigned short Vt_s[64 * 72];     // [d][key]

    const int t = threadIdx.x;
    const int qb = blockIdx.x, h = blockIdx.y, b = blockIdx.z;
    const int t0 = qb * 128;
    const int wave = t >> 6, lane = t & 63;
    const int lrow = lane & 15;
    const int lk8 = (lane >> 4) * 8;
    const int wq = wave * 32;                 // wave's query-row offset in tile
    const int rq = (lane >> 4) * 4;           // C-layout row base

    // Stage Q tile (hi+lo): 128x64 bf16 each. Covered by 2 barriers below.
#pragma unroll
    for (int u = 0; u < 4; ++u) {
        int slot = u * 256 + t;
        int row = slot >> 3;
        int d8 = (slot & 7) * 8;
        size_t g = (size_t)(b * SS + t0 + row) * SH + h * HD + d8;
        *(uint4*)&Qhi_s[row * 72 + d8] = *(const uint4*)(Qhig + g);
        *(uint4*)&Qlo_s[row * 72 + d8] = *(const uint4*)(Qlog + g);
    }

    f32x4 o[2][4];
    float lsum[2][4];
#pragma unroll
    for (int i = 0; i < 2; ++i)
#pragma unroll
        for (int j = 0; j < 4; ++j) o[i][j] = (f32x4){0.f, 0.f, 0.f, 0.f};
#pragma unroll
    for (int i = 0; i < 2; ++i)
#pragma unroll
        for (int r = 0; r < 4; ++r) lsum[i][r] = 0.f;

    int cl = t0 - (WIN - 1);
    cl = cl < 0 ? 0 : cl;
    const int c_lo = cl >> 6;
    const int c_hi = (t0 >> 6) + 1;

    for (int c = c_lo; c <= c_hi; ++c) {
        const int key0 = c * 64;
        __syncthreads();   // prev PV reads of P/Vt done (also orders Q staging)
#pragma unroll
        for (int u = 0; u < 2; ++u) {
            int slot = u * 256 + t;
            int row = slot >> 3;           // key idx for K, d idx for Vt
            int e8 = (slot & 7) * 8;
            size_t gk = (size_t)(b * SS + key0 + row) * SH + h * HD + e8;
            *(uint4*)&K_s[row * 72 + e8] = *(const uint4*)(Khig + gk);
            *(uint4*)&K_s[4608 + row * 72 + e8] = *(const uint4*)(Klog + gk);
            size_t gv = (size_t)(h * HD + row) * (SB * SS) + b * SS + key0 + e8;
            *(uint4*)&Vt_s[row * 72 + e8] = *(const uint4*)(Vtg + gv);
        }
        __syncthreads();

        // S = Q @ K^T (bf16x3), K-dim = 64 = 2 MFMA k-steps.
        f32x4 s[2][4];
#pragma unroll
        for (int i = 0; i < 2; ++i)
#pragma unroll
            for (int j = 0; j < 4; ++j) s[i][j] = (f32x4){0.f, 0.f, 0.f, 0.f};
#pragma unroll
        for (int ki = 0; ki < 2; ++ki) {
            bf16x8 ah[2], al[2];
#pragma unroll
            for (int i = 0; i < 2; ++i) {
                int off = (wq + i * 16 + lrow) * 72 + ki * 32 + lk8;
                ah[i] = *(const bf16x8*)&Qhi_s[off];
                al[i] = *(const bf16x8*)&Qlo_s[off];
            }
#pragma unroll
            for (int j = 0; j < 4; ++j) {
                int offb = (j * 16 + lrow) * 72 + ki * 32 + lk8;
                bf16x8 bh = *(const bf16x8*)&K_s[offb];
                bf16x8 bl = *(const bf16x8*)&K_s[4608 + offb];
#pragma unroll
                for (int i = 0; i < 2; ++i) {
                    s[i][j] = __builtin_amdgcn_mfma_f32_16x16x32_bf16(ah[i], bh, s[i][j], 0, 0, 0);
                    s[i][j] = __builtin_amdgcn_mfma_f32_16x16x32_bf16(ah[i], bl, s[i][j], 0, 0, 0);
                    s[i][j] = __builtin_amdgcn_mfma_f32_16x16x32_bf16(al[i], bh, s[i][j], 0, 0, 0);
                }
            }
        }
        __syncthreads();   // all waves done reading K before P overlays it

        // mask + exp (fp32), row-sum partials, P -> bf16 LDS (A-layout rows).
        // No barrier needed before PV: each wave writes/reads only its own P rows.
#pragma unroll
        for (int i = 0; i < 2; ++i)
#pragma unroll
            for (int j = 0; j < 4; ++j) {
                int jg = key0 + j * 16 + lrow;
#pragma unroll
                for (int r = 0; r < 4; ++r) {
                    int qg = t0 + wq + i * 16 + rq + r;
                    float p = (jg <= qg && jg > qg - WIN) ? __expf(s[i][j][r]) : 0.f;
                    lsum[i][r] += p;
                    K_s[(wq + i * 16 + rq + r) * 72 + j * 16 + lrow] = pk_bf16(p, 0.f).x;
                }
            }

        // ctx += P @ V  (keys = reduction dim, 2 MFMA k-steps)
#pragma unroll
        for (int ki = 0; ki < 2; ++ki) {
            bf16x8 pf[2];
#pragma unroll
            for (int i = 0; i < 2; ++i)
                pf[i] = *(const bf16x8*)&K_s[(wq + i * 16 + lrow) * 72 + ki * 32 + lk8];
#pragma unroll
            for (int j = 0; j < 4; ++j) {
                bf16x8 vf = *(const bf16x8*)&Vt_s[(j * 16 + lrow) * 72 + ki * 32 + lk8];
#pragma unroll
                for (int i = 0; i < 2; ++i)
                    o[i][j] = __builtin_amdgcn_mfma_f32_16x16x32_bf16(pf[i], vf, o[i][j], 0, 0, 0);
            }
        }
    }

    // Full row sums: reduce over the 16 lanes sharing each row.
#pragma unroll
    for (int i = 0; i < 2; ++i)
#pragma unroll
        for (int r = 0; r < 4; ++r) {
#pragma unroll
            for (int m = 1; m < 16; m <<= 1)
                lsum[i][r] += __shfl_xor(lsum[i][r], m);
        }

    // Normalize, ablation-mask, bf16 -> LDS (reuse Qhi_s: each wave owns its rows)
#pragma unroll
    for (int i = 0; i < 2; ++i)
#pragma unroll
        for (int r = 0; r < 4; ++r) {
            float inv = 1.f / lsum[i][r];
            int ql = wq + i * 16 + rq + r;
#pragma unroll
            for (int j = 0; j < 4; ++j) {
                int d = j * 16 + lrow;
                float msk = amask[(size_t)(b * SS + t0 + ql) * SH + h * HD + d];
                Qhi_s[ql * 72 + d] = pk_bf16(o[i][j][r] * inv * msk, 0.f).x;
            }
        }
    __syncthreads();
#pragma unroll
    for (int u = 0; u < 4; ++u) {
        int slot = u * 256 + t;
        int row = slot >> 3;
        int d8 = (slot & 7) * 8;
        *(uint4*)(ctxg + (size_t)(b * SS + t0 + row) * SH + h * HD + d8) =
            *(const uint4*)&Qhi_s[row * 72 + d8];
    }
}

extern "C" void kernel_launch(void* const* d_in, const int* in_sizes, int n_in,
                              void* d_out, int out_size, void* d_ws, size_t ws_size,
                              hipStream_t stream)
{
    const float* x     = (const float*)d_in[0];
    const float* xc    = (const float*)d_in[1];
    const float* amask = (const float*)d_in[2];
    const float* Wq    = (const float*)d_in[3];
    const float* Wk    = (const float*)d_in[4];
    const float* Wv    = (const float*)d_in[5];
    const float* Wo    = (const float*)d_in[6];
    const float* bo    = (const float*)d_in[7];
    float* out = (float*)d_out;

    const int M = SB * SS;                     // 8192
    const size_t BUF = (size_t)M * SH;         // elements per buffer
    unsigned short* Qhi = (unsigned short*)d_ws;   // 6 x 16MB = 96MB total
    unsigned short* Qlo = Qhi + BUF;
    unsigned short* Khi = Qlo + BUF;
    unsigned short* Klo = Khi + BUF;
    unsigned short* Vt  = Klo + BUF;
    unsigned short* ctx = Vt + BUF;

    dim3 gg(M / 128, SH / 128);
    dim3 gb(256);
    hipLaunchKernelGGL((gemm_mfma<1, 0, 1>), gg, gb, 0, stream,
                       (const void*)x,  Wq, bo, (void*)Qhi, (void*)Qlo, M, SH, SH);
    hipLaunchKernelGGL((gemm_mfma<1, 0, 1>), gg, gb, 0, stream,
                       (const void*)xc, Wk, bo, (void*)Khi, (void*)Klo, M, SH, SH);
    hipLaunchKernelGGL((gemm_mfma<0, 0, 2>), gg, gb, 0, stream,
                       (const void*)xc, Wv, bo, (void*)Vt, (void*)nullptr, M, SH, SH);

    hipLaunchKernelGGL(attn_mfma, dim3(SS / 128, NH, SB), dim3(256), 0, stream,
                       Qhi, Qlo, Khi, Klo, Vt, amask, ctx);

    hipLaunchKernelGGL((gemm_mfma<0, 1, 0>), gg, gb, 0, stream,
                       (const void*)ctx, Wo, bo, (void*)out, (void*)nullptr, M, SH, SH);
}

// Round 4
// 387.424 us; speedup vs baseline: 3.1146x; 1.0661x over previous
//
#include <hip/hip_runtime.h>
#include <hip/hip_bf16.h>
#include <cstddef>

#define SB 4
#define SS 2048
#define SH 1024
#define NH 16
#define HD 64
#define WIN 256
#define PITCH 40   // LDS row pitch in shorts: 80B = 16B-aligned, 20-bank rotation -> 2-way (free)

typedef __attribute__((ext_vector_type(8))) short bf16x8;
typedef __attribute__((ext_vector_type(4))) float f32x4;

static __device__ __forceinline__ ushort2 pk_bf16(float a, float b) {
    __hip_bfloat162 h = __float22bfloat162_rn(make_float2(a, b));
    union { __hip_bfloat162 h2; ushort2 u2; } u;
    u.h2 = h;
    return u.u2;
}
static __device__ __forceinline__ float bf_hi_f(unsigned short h) {
    return __uint_as_float(((unsigned)h) << 16);
}
static __device__ __forceinline__ unsigned short pk1(float a) {
    return pk_bf16(a, 0.f).x;
}

// Pre-convert fp32 -> bf16 hi (+ lo residual). One float4 per thread.
__global__ __launch_bounds__(256) void cvt_split(
    const float* __restrict__ src, unsigned short* __restrict__ hi,
    unsigned short* __restrict__ lo, int n4, int do_lo)
{
    int idx = blockIdx.x * 256 + threadIdx.x;
    if (idx >= n4) return;
    float4 v = ((const float4*)src)[idx];
    ushort2 h01 = pk_bf16(v.x, v.y), h23 = pk_bf16(v.z, v.w);
    ((ushort4*)hi)[idx] = make_ushort4(h01.x, h01.y, h23.x, h23.y);
    if (do_lo) {
        ushort2 l01 = pk_bf16(v.x - bf_hi_f(h01.x), v.y - bf_hi_f(h01.y));
        ushort2 l23 = pk_bf16(v.z - bf_hi_f(h23.x), v.w - bf_hi_f(h23.y));
        ((ushort4*)lo)[idx] = make_ushort4(l01.x, l01.y, l23.x, l23.y);
    }
}

// C[M,N] = A[M,K] @ W[N,K]^T. 128x128 tile, BK=32, 4 waves, 4x4 16x16x32 MFMAs.
// W is PRE-CONVERTED bf16 (hi [+lo]) -> staging is pure uint4 copy.
// AMODE: 0 = A fp32, split hi/lo cvt in staging (3-MFMA error-compensated)
//        1 = A fp32, hi only
//        2 = A bf16, pure copy
// OUTM:  0 = fp32 + bias -> C1(float*)
//        1 = hi/lo bf16  -> C1,C2(ushort*)                 [Q,K]
//        2 = C^T[n][m] bf16 via LDS transpose -> C1(ushort*) [V]
template<int AMODE, int OUTM>
__global__ __launch_bounds__(256) void gemm2(
    const void* __restrict__ Ap,
    const unsigned short* __restrict__ Wh, const unsigned short* __restrict__ Wl,
    const float* __restrict__ bias, void* __restrict__ C1v, void* __restrict__ C2v,
    int M, int N, int K)
{
    constexpr int SPLIT = (AMODE == 0);
    // split: Ah|Bh|Al|Bl (40KB). plain: Ah|Bh (20KB, also hosts 17KB transpose buf).
    __shared__ __align__(16) unsigned short smem[(SPLIT ? 4 : 2) * 128 * PITCH];
    unsigned short* Ah = smem;
    unsigned short* Bh = smem + 128 * PITCH;
    unsigned short* Al = SPLIT ? smem + 2 * 128 * PITCH : smem;
    unsigned short* Bl = SPLIT ? smem + 3 * 128 * PITCH : smem;

    const int tid = threadIdx.x;
    const int m0 = blockIdx.x * 128;
    const int n0 = blockIdx.y * 128;
    const int wave = tid >> 6;
    const int lane = tid & 63;
    const int wm = (wave & 1) * 64;
    const int wn = (wave >> 1) * 64;
    const int lrow = lane & 15;
    const int lk8 = (lane >> 4) * 8;
    const int rq = (lane >> 4) * 4;

    f32x4 acc[4][4];
#pragma unroll
    for (int i = 0; i < 4; ++i)
#pragma unroll
        for (int j = 0; j < 4; ++j)
            acc[i][j] = (f32x4){0.f, 0.f, 0.f, 0.f};

    for (int k0 = 0; k0 < K; k0 += 32) {
        __syncthreads();
        // W tiles: 512 uint4 copies (2/thread), no cvt.
#pragma unroll
        for (int u = 0; u < 2; ++u) {
            int slot = u * 256 + tid;
            int row = slot >> 2;
            int k8 = (slot & 3) * 8;
            *(uint4*)&Bh[row * PITCH + k8] =
                *(const uint4*)(Wh + (size_t)(n0 + row) * K + k0 + k8);
            if (SPLIT)
                *(uint4*)&Bl[row * PITCH + k8] =
                    *(const uint4*)(Wl + (size_t)(n0 + row) * K + k0 + k8);
        }
        // A tiles
        if (AMODE == 2) {
            const unsigned short* Ab = (const unsigned short*)Ap;
#pragma unroll
            for (int u = 0; u < 2; ++u) {
                int slot = u * 256 + tid;
                int row = slot >> 2;
                int k8 = (slot & 3) * 8;
                *(uint4*)&Ah[row * PITCH + k8] =
                    *(const uint4*)(Ab + (size_t)(m0 + row) * K + k0 + k8);
            }
        } else {
            const float* Af = (const float*)Ap;
#pragma unroll
            for (int u = 0; u < 4; ++u) {
                int f = u * 256 + tid;
                int row = f >> 3;
                int kc = (f & 7) * 4;
                float4 av = *(const float4*)(Af + (size_t)(m0 + row) * K + k0 + kc);
                ushort2 h01 = pk_bf16(av.x, av.y), h23 = pk_bf16(av.z, av.w);
                *(ushort4*)&Ah[row * PITCH + kc] = make_ushort4(h01.x, h01.y, h23.x, h23.y);
                if (SPLIT) {
                    ushort2 l01 = pk_bf16(av.x - bf_hi_f(h01.x), av.y - bf_hi_f(h01.y));
                    ushort2 l23 = pk_bf16(av.z - bf_hi_f(h23.x), av.w - bf_hi_f(h23.y));
                    *(ushort4*)&Al[row * PITCH + kc] = make_ushort4(l01.x, l01.y, l23.x, l23.y);
                }
            }
        }
        __syncthreads();

        bf16x8 bhi[4], blo[4];
#pragma unroll
        for (int j = 0; j < 4; ++j) {
            int off = (wn + j * 16 + lrow) * PITCH + lk8;
            bhi[j] = *(const bf16x8*)&Bh[off];
            if (SPLIT) blo[j] = *(const bf16x8*)&Bl[off];
        }
#pragma unroll
        for (int i = 0; i < 4; ++i) {
            int off = (wm + i * 16 + lrow) * PITCH + lk8;
            bf16x8 ahi = *(const bf16x8*)&Ah[off];
            bf16x8 alo;
            if (SPLIT) alo = *(const bf16x8*)&Al[off];
#pragma unroll
            for (int j = 0; j < 4; ++j) {
                acc[i][j] = __builtin_amdgcn_mfma_f32_16x16x32_bf16(ahi, bhi[j], acc[i][j], 0, 0, 0);
                if (SPLIT) {
                    acc[i][j] = __builtin_amdgcn_mfma_f32_16x16x32_bf16(ahi, blo[j], acc[i][j], 0, 0, 0);
                    acc[i][j] = __builtin_amdgcn_mfma_f32_16x16x32_bf16(alo, bhi[j], acc[i][j], 0, 0, 0);
                }
            }
        }
    }

    // C/D layout: col = lane&15, row = (lane>>4)*4 + reg.
    if (OUTM == 0) {
        float* C = (float*)C1v;
#pragma unroll
        for (int i = 0; i < 4; ++i) {
            int rbase = m0 + wm + i * 16 + rq;
#pragma unroll
            for (int j = 0; j < 4; ++j) {
                int col = n0 + wn + j * 16 + lrow;
                float badd = bias[col];
#pragma unroll
                for (int r = 0; r < 4; ++r)
                    C[(size_t)(rbase + r) * N + col] = acc[i][j][r] + badd;
            }
        }
    } else if (OUTM == 1) {
        unsigned short* Ch = (unsigned short*)C1v;
        unsigned short* Cl = (unsigned short*)C2v;
#pragma unroll
        for (int i = 0; i < 4; ++i) {
            int rbase = m0 + wm + i * 16 + rq;
#pragma unroll
            for (int j = 0; j < 4; ++j) {
                int col = n0 + wn + j * 16 + lrow;
#pragma unroll
                for (int r = 0; r < 4; ++r) {
                    float v = acc[i][j][r];
                    unsigned short hi = pk1(v);
                    Ch[(size_t)(rbase + r) * N + col] = hi;
                    Cl[(size_t)(rbase + r) * N + col] = pk1(v - bf_hi_f(hi));
                }
            }
        }
    } else {
        // Transposed bf16 out via LDS (pitch 136 shorts: 16B-aligned, 4-bank rot).
        unsigned short* Ct = (unsigned short*)C1v;   // C^T[n][m], row stride M
        unsigned short* T = smem;                    // 64 x 136 shorts = 17408B
#pragma unroll
        for (int p = 0; p < 2; ++p) {
            __syncthreads();
            if (wn == p * 64) {
#pragma unroll
                for (int i = 0; i < 4; ++i) {
                    int mloc = wm + i * 16 + rq;
#pragma unroll
                    for (int j = 0; j < 4; ++j) {
                        int cl = j * 16 + lrow;
                        *(ushort4*)&T[cl * 136 + mloc] = make_ushort4(
                            pk1(acc[i][j][0]), pk1(acc[i][j][1]),
                            pk1(acc[i][j][2]), pk1(acc[i][j][3]));
                    }
                }
            }
            __syncthreads();
#pragma unroll
            for (int u = 0; u < 4; ++u) {
                int slot = u * 256 + tid;
                int cl = slot >> 4;
                int m8 = (slot & 15) * 8;
                *(uint4*)(Ct + (size_t)(n0 + p * 64 + cl) * M + m0 + m8) =
                    *(const uint4*)&T[cl * 136 + m8];
            }
        }
    }
}

// MFMA flash attention over the local causal window (unchanged from R3 except
// ctxg may alias Qhig: each block exclusively owns its (rows, head) slice,
// reads Q fully into LDS before any ctx write -> race-free, so no __restrict__
// on those two).
__global__ __launch_bounds__(256) void attn_mfma(
    const unsigned short* Qhig, const unsigned short* Qlog,
    const unsigned short* __restrict__ Khig, const unsigned short* __restrict__ Klog,
    const unsigned short* __restrict__ Vtg,  const float* __restrict__ amask,
    unsigned short* ctxg)
{
    __shared__ __align__(16) unsigned short Qhi_s[128 * 72];
    __shared__ __align__(16) unsigned short Qlo_s[128 * 72];
    __shared__ __align__(16) unsigned short K_s[2 * 64 * 72];
    __shared__ __align__(16) unsigned short Vt_s[64 * 72];

    const int t = threadIdx.x;
    const int qb = blockIdx.x, h = blockIdx.y, b = blockIdx.z;
    const int t0 = qb * 128;
    const int wave = t >> 6, lane = t & 63;
    const int lrow = lane & 15;
    const int lk8 = (lane >> 4) * 8;
    const int wq = wave * 32;
    const int rq = (lane >> 4) * 4;

#pragma unroll
    for (int u = 0; u < 4; ++u) {
        int slot = u * 256 + t;
        int row = slot >> 3;
        int d8 = (slot & 7) * 8;
        size_t g = (size_t)(b * SS + t0 + row) * SH + h * HD + d8;
        *(uint4*)&Qhi_s[row * 72 + d8] = *(const uint4*)(Qhig + g);
        *(uint4*)&Qlo_s[row * 72 + d8] = *(const uint4*)(Qlog + g);
    }

    f32x4 o[2][4];
    float lsum[2][4];
#pragma unroll
    for (int i = 0; i < 2; ++i)
#pragma unroll
        for (int j = 0; j < 4; ++j) o[i][j] = (f32x4){0.f, 0.f, 0.f, 0.f};
#pragma unroll
    for (int i = 0; i < 2; ++i)
#pragma unroll
        for (int r = 0; r < 4; ++r) lsum[i][r] = 0.f;

    int cl = t0 - (WIN - 1);
    cl = cl < 0 ? 0 : cl;
    const int c_lo = cl >> 6;
    const int c_hi = (t0 >> 6) + 1;

    for (int c = c_lo; c <= c_hi; ++c) {
        const int key0 = c * 64;
        __syncthreads();
#pragma unroll
        for (int u = 0; u < 2; ++u) {
            int slot = u * 256 + t;
            int row = slot >> 3;
            int e8 = (slot & 7) * 8;
            size_t gk = (size_t)(b * SS + key0 + row) * SH + h * HD + e8;
            *(uint4*)&K_s[row * 72 + e8] = *(const uint4*)(Khig + gk);
            *(uint4*)&K_s[4608 + row * 72 + e8] = *(const uint4*)(Klog + gk);
            size_t gv = (size_t)(h * HD + row) * (SB * SS) + b * SS + key0 + e8;
            *(uint4*)&Vt_s[row * 72 + e8] = *(const uint4*)(Vtg + gv);
        }
        __syncthreads();

        f32x4 s[2][4];
#pragma unroll
        for (int i = 0; i < 2; ++i)
#pragma unroll
            for (int j = 0; j < 4; ++j) s[i][j] = (f32x4){0.f, 0.f, 0.f, 0.f};
#pragma unroll
        for (int ki = 0; ki < 2; ++ki) {
            bf16x8 ah[2], al[2];
#pragma unroll
            for (int i = 0; i < 2; ++i) {
                int off = (wq + i * 16 + lrow) * 72 + ki * 32 + lk8;
                ah[i] = *(const bf16x8*)&Qhi_s[off];
                al[i] = *(const bf16x8*)&Qlo_s[off];
            }
#pragma unroll
            for (int j = 0; j < 4; ++j) {
                int offb = (j * 16 + lrow) * 72 + ki * 32 + lk8;
                bf16x8 bh = *(const bf16x8*)&K_s[offb];
                bf16x8 bl = *(const bf16x8*)&K_s[4608 + offb];
#pragma unroll
                for (int i = 0; i < 2; ++i) {
                    s[i][j] = __builtin_amdgcn_mfma_f32_16x16x32_bf16(ah[i], bh, s[i][j], 0, 0, 0);
                    s[i][j] = __builtin_amdgcn_mfma_f32_16x16x32_bf16(ah[i], bl, s[i][j], 0, 0, 0);
                    s[i][j] = __builtin_amdgcn_mfma_f32_16x16x32_bf16(al[i], bh, s[i][j], 0, 0, 0);
                }
            }
        }
        __syncthreads();

#pragma unroll
        for (int i = 0; i < 2; ++i)
#pragma unroll
            for (int j = 0; j < 4; ++j) {
                int jg = key0 + j * 16 + lrow;
#pragma unroll
                for (int r = 0; r < 4; ++r) {
                    int qg = t0 + wq + i * 16 + rq + r;
                    float p = (jg <= qg && jg > qg - WIN) ? __expf(s[i][j][r]) : 0.f;
                    lsum[i][r] += p;
                    K_s[(wq + i * 16 + rq + r) * 72 + j * 16 + lrow] = pk1(p);
                }
            }

#pragma unroll
        for (int ki = 0; ki < 2; ++ki) {
            bf16x8 pf[2];
#pragma unroll
            for (int i = 0; i < 2; ++i)
                pf[i] = *(const bf16x8*)&K_s[(wq + i * 16 + lrow) * 72 + ki * 32 + lk8];
#pragma unroll
            for (int j = 0; j < 4; ++j) {
                bf16x8 vf = *(const bf16x8*)&Vt_s[(j * 16 + lrow) * 72 + ki * 32 + lk8];
#pragma unroll
                for (int i = 0; i < 2; ++i)
                    o[i][j] = __builtin_amdgcn_mfma_f32_16x16x32_bf16(pf[i], vf, o[i][j], 0, 0, 0);
            }
        }
    }

#pragma unroll
    for (int i = 0; i < 2; ++i)
#pragma unroll
        for (int r = 0; r < 4; ++r) {
#pragma unroll
            for (int m = 1; m < 16; m <<= 1)
                lsum[i][r] += __shfl_xor(lsum[i][r], m);
        }

#pragma unroll
    for (int i = 0; i < 2; ++i)
#pragma unroll
        for (int r = 0; r < 4; ++r) {
            float inv = 1.f / lsum[i][r];
            int ql = wq + i * 16 + rq + r;
#pragma unroll
            for (int j = 0; j < 4; ++j) {
                int d = j * 16 + lrow;
                float msk = amask[(size_t)(b * SS + t0 + ql) * SH + h * HD + d];
                Qhi_s[ql * 72 + d] = pk1(o[i][j][r] * inv * msk);
            }
        }
    __syncthreads();
#pragma unroll
    for (int u = 0; u < 4; ++u) {
        int slot = u * 256 + t;
        int row = slot >> 3;
        int d8 = (slot & 7) * 8;
        *(uint4*)(ctxg + (size_t)(b * SS + t0 + row) * SH + h * HD + d8) =
            *(const uint4*)&Qhi_s[row * 72 + d8];
    }
}

extern "C" void kernel_launch(void* const* d_in, const int* in_sizes, int n_in,
                              void* d_out, int out_size, void* d_ws, size_t ws_size,
                              hipStream_t stream)
{
    const float* x     = (const float*)d_in[0];
    const float* xc    = (const float*)d_in[1];
    const float* amask = (const float*)d_in[2];
    const float* Wq    = (const float*)d_in[3];
    const float* Wk    = (const float*)d_in[4];
    const float* Wv    = (const float*)d_in[5];
    const float* Wo    = (const float*)d_in[6];
    const float* bo    = (const float*)d_in[7];
    float* out = (float*)d_out;

    const int M = SB * SS;                       // 8192
    const size_t BUF = (size_t)M * SH;           // 8.4M elems = 16MB bf16
    const size_t WBUF = (size_t)SH * SH;         // 1M elems = 2MB bf16
    unsigned short* Qhi = (unsigned short*)d_ws; // ctx aliases Qhi (safe, see attn)
    unsigned short* Qlo = Qhi + BUF;
    unsigned short* Khi = Qlo + BUF;
    unsigned short* Klo = Khi + BUF;
    unsigned short* Vt  = Klo + BUF;
    unsigned short* Wqh = Vt + BUF;              // weights: 6 x 2MB, total 92MB ws
    unsigned short* Wql = Wqh + WBUF;
    unsigned short* Wkh = Wql + WBUF;
    unsigned short* Wkl = Wkh + WBUF;
    unsigned short* Wvh = Wkl + WBUF;
    unsigned short* Woh = Wvh + WBUF;
    unsigned short* ctx = Qhi;

    const int n4 = SH * SH / 4;                  // 262144 float4 per weight
    hipLaunchKernelGGL(cvt_split, dim3(n4 / 256), dim3(256), 0, stream, Wq, Wqh, Wql, n4, 1);
    hipLaunchKernelGGL(cvt_split, dim3(n4 / 256), dim3(256), 0, stream, Wk, Wkh, Wkl, n4, 1);
    hipLaunchKernelGGL(cvt_split, dim3(n4 / 256), dim3(256), 0, stream, Wv, Wvh, (unsigned short*)nullptr, n4, 0);
    hipLaunchKernelGGL(cvt_split, dim3(n4 / 256), dim3(256), 0, stream, Wo, Woh, (unsigned short*)nullptr, n4, 0);

    dim3 gg(M / 128, SH / 128);
    dim3 gb(256);
    hipLaunchKernelGGL((gemm2<0, 1>), gg, gb, 0, stream,
                       (const void*)x,  Wqh, Wql, bo, (void*)Qhi, (void*)Qlo, M, SH, SH);
    hipLaunchKernelGGL((gemm2<0, 1>), gg, gb, 0, stream,
                       (const void*)xc, Wkh, Wkl, bo, (void*)Khi, (void*)Klo, M, SH, SH);
    hipLaunchKernelGGL((gemm2<1, 2>), gg, gb, 0, stream,
                       (const void*)xc, Wvh, (const unsigned short*)nullptr, bo, (void*)Vt, (void*)nullptr, M, SH, SH);

    hipLaunchKernelGGL(attn_mfma, dim3(SS / 128, NH, SB), dim3(256), 0, stream,
                       Qhi, Qlo, Khi, Klo, Vt, amask, ctx);

    hipLaunchKernelGGL((gemm2<2, 0>), gg, gb, 0, stream,
                       (const void*)ctx, Woh, (const unsigned short*)nullptr, bo, (void*)out, (void*)nullptr, M, SH, SH);
}

// Round 6
// 319.069 us; speedup vs baseline: 3.7818x; 1.2142x over previous
//
#include <hip/hip_runtime.h>
#include <hip/hip_bf16.h>
#include <cstddef>

#define SB 4
#define SS 2048
#define SH 1024
#define NH 16
#define HD 64
#define WIN 256
#define PITCH 40   // GEMM LDS row pitch in elems: 80B = 16B-aligned, 20-bank rotation

typedef __attribute__((ext_vector_type(8))) short bf16x8;
typedef __attribute__((ext_vector_type(8))) _Float16 f16x8;
typedef __attribute__((ext_vector_type(2))) __fp16 fp16v2;
typedef __attribute__((ext_vector_type(4))) float f32x4;

static __device__ __forceinline__ ushort2 pk_bf16(float a, float b) {
    __hip_bfloat162 h = __float22bfloat162_rn(make_float2(a, b));
    union { __hip_bfloat162 h2; ushort2 u2; } u;
    u.h2 = h;
    return u.u2;
}
static __device__ __forceinline__ unsigned short pk1(float a) {
    return pk_bf16(a, 0.f).x;
}

// fp32 -> f16, one float4 -> 4 halves (8B) per thread.
__global__ __launch_bounds__(256) void cvt_f16(
    const float* __restrict__ src, _Float16* __restrict__ dst, int n4)
{
    int idx = blockIdx.x * 256 + threadIdx.x;
    if (idx >= n4) return;
    float4 v = ((const float4*)src)[idx];
    union { fp16v2 h[2]; uint2 u; } t;
    t.h[0] = __builtin_amdgcn_cvt_pkrtz(v.x, v.y);
    t.h[1] = __builtin_amdgcn_cvt_pkrtz(v.z, v.w);
    ((uint2*)dst)[idx] = t.u;
}

// C[M,N] = A[M,K] @ W[N,K]^T, all-f16 operands (pre-converted), fp32 acc.
// 128x128 tile, BK=32, 4 waves, 4x4 grid of 16x16x32 f16 MFMAs, pure-copy staging.
// OUTM: 0 = fp32 + bias -> C1(float*)              [O]
//       1 = f16 -> C1(_Float16*)                   [Q,K]
//       2 = C^T[n][m] bf16 via LDS transpose -> C1 [V]
template<int OUTM>
__global__ __launch_bounds__(256) void gemm3(
    const _Float16* __restrict__ A, const _Float16* __restrict__ W,
    const float* __restrict__ bias, void* __restrict__ C1v,
    int M, int N, int K)
{
    __shared__ __align__(16) unsigned short smem[2 * 128 * PITCH]; // 20KB
    _Float16* Ah = (_Float16*)smem;
    _Float16* Bh = (_Float16*)smem + 128 * PITCH;

    const int tid = threadIdx.x;
    const int m0 = blockIdx.x * 128;
    const int n0 = blockIdx.y * 128;
    const int wave = tid >> 6;
    const int lane = tid & 63;
    const int wm = (wave & 1) * 64;
    const int wn = (wave >> 1) * 64;
    const int lrow = lane & 15;
    const int lk8 = (lane >> 4) * 8;
    const int rq = (lane >> 4) * 4;

    f32x4 acc[4][4];
#pragma unroll
    for (int i = 0; i < 4; ++i)
#pragma unroll
        for (int j = 0; j < 4; ++j)
            acc[i][j] = (f32x4){0.f, 0.f, 0.f, 0.f};

    for (int k0 = 0; k0 < K; k0 += 32) {
        __syncthreads();
        // A,W tiles: 128x32 f16 = 8KB each = 512 uint4, 2/thread each.
#pragma unroll
        for (int u = 0; u < 2; ++u) {
            int slot = u * 256 + tid;
            int row = slot >> 2;
            int k8 = (slot & 3) * 8;
            *(uint4*)&Ah[row * PITCH + k8] =
                *(const uint4*)(A + (size_t)(m0 + row) * K + k0 + k8);
            *(uint4*)&Bh[row * PITCH + k8] =
                *(const uint4*)(W + (size_t)(n0 + row) * K + k0 + k8);
        }
        __syncthreads();

        f16x8 bf[4];
#pragma unroll
        for (int j = 0; j < 4; ++j)
            bf[j] = *(const f16x8*)&Bh[(wn + j * 16 + lrow) * PITCH + lk8];
#pragma unroll
        for (int i = 0; i < 4; ++i) {
            f16x8 af = *(const f16x8*)&Ah[(wm + i * 16 + lrow) * PITCH + lk8];
#pragma unroll
            for (int j = 0; j < 4; ++j)
                acc[i][j] = __builtin_amdgcn_mfma_f32_16x16x32_f16(af, bf[j], acc[i][j], 0, 0, 0);
        }
    }

    // C/D layout: col = lane&15, row = (lane>>4)*4 + reg.
    if (OUTM == 0) {
        float* C = (float*)C1v;
#pragma unroll
        for (int i = 0; i < 4; ++i) {
            int rbase = m0 + wm + i * 16 + rq;
#pragma unroll
            for (int j = 0; j < 4; ++j) {
                int col = n0 + wn + j * 16 + lrow;
                float badd = bias[col];
#pragma unroll
                for (int r = 0; r < 4; ++r)
                    C[(size_t)(rbase + r) * N + col] = acc[i][j][r] + badd;
            }
        }
    } else if (OUTM == 1) {
        _Float16* C = (_Float16*)C1v;
#pragma unroll
        for (int i = 0; i < 4; ++i) {
            int rbase = m0 + wm + i * 16 + rq;
#pragma unroll
            for (int j = 0; j < 4; ++j) {
                int col = n0 + wn + j * 16 + lrow;
#pragma unroll
                for (int r = 0; r < 4; ++r)
                    C[(size_t)(rbase + r) * N + col] = (_Float16)acc[i][j][r];
            }
        }
    } else {
        // Transposed bf16 out via LDS (pitch 136 shorts: 16B-aligned, 4-bank rot).
        unsigned short* Ct = (unsigned short*)C1v;   // C^T[n][m], row stride M
        unsigned short* T = smem;                    // 64 x 136 shorts = 17408B
#pragma unroll
        for (int p = 0; p < 2; ++p) {
            __syncthreads();
            if (wn == p * 64) {
#pragma unroll
                for (int i = 0; i < 4; ++i) {
                    int mloc = wm + i * 16 + rq;
#pragma unroll
                    for (int j = 0; j < 4; ++j) {
                        int cl = j * 16 + lrow;
                        *(ushort4*)&T[cl * 136 + mloc] = make_ushort4(
                            pk1(acc[i][j][0]), pk1(acc[i][j][1]),
                            pk1(acc[i][j][2]), pk1(acc[i][j][3]));
                    }
                }
            }
            __syncthreads();
#pragma unroll
            for (int u = 0; u < 4; ++u) {
                int slot = u * 256 + tid;
                int cl = slot >> 4;
                int m8 = (slot & 15) * 8;
                *(uint4*)(Ct + (size_t)(n0 + p * 64 + cl) * M + m0 + m8) =
                    *(const uint4*)&T[cl * 136 + m8];
            }
        }
    }
}

// MFMA flash attention over the local causal window.
// Q,K f16 (S = single f16 MFMA); P,V bf16 (p = exp(s) up to ~e^47 needs bf16
// range; no online max needed since fp32/bf16 can't overflow at |s|<~60).
// ctx (f16 out) may alias Qh: block reads its Q slice into LDS before any ctx
// write and owns that slice exclusively -> race-free.
__global__ __launch_bounds__(256) void attn_mfma(
    const _Float16* Qg, const _Float16* __restrict__ Kg,
    const unsigned short* __restrict__ Vtg, const float* __restrict__ amask,
    _Float16* ctxg)
{
    __shared__ __align__(16) _Float16 Q_s[128 * 72];        // 18KB
    __shared__ __align__(16) _Float16 K_s[64 * 72];         // 9KB
    __shared__ __align__(16) unsigned short P_s[128 * 72];  // 18KB bf16
    __shared__ __align__(16) unsigned short Vt_s[64 * 72];  // 9KB bf16 [d][key]

    const int t = threadIdx.x;
    const int qb = blockIdx.x, h = blockIdx.y, b = blockIdx.z;
    const int t0 = qb * 128;
    const int wave = t >> 6, lane = t & 63;
    const int lrow = lane & 15;
    const int lk8 = (lane >> 4) * 8;
    const int wq = wave * 32;
    const int rq = (lane >> 4) * 4;

#pragma unroll
    for (int u = 0; u < 4; ++u) {
        int slot = u * 256 + t;
        int row = slot >> 3;
        int d8 = (slot & 7) * 8;
        *(uint4*)&Q_s[row * 72 + d8] =
            *(const uint4*)(Qg + (size_t)(b * SS + t0 + row) * SH + h * HD + d8);
    }

    f32x4 o[2][4];
    float lsum[2][4];
#pragma unroll
    for (int i = 0; i < 2; ++i)
#pragma unroll
        for (int j = 0; j < 4; ++j) o[i][j] = (f32x4){0.f, 0.f, 0.f, 0.f};
#pragma unroll
    for (int i = 0; i < 2; ++i)
#pragma unroll
        for (int r = 0; r < 4; ++r) lsum[i][r] = 0.f;

    int cl = t0 - (WIN - 1);
    cl = cl < 0 ? 0 : cl;
    const int c_lo = cl >> 6;
    const int c_hi = (t0 >> 6) + 1;

    for (int c = c_lo; c <= c_hi; ++c) {
        const int key0 = c * 64;
        __syncthreads();   // prev-iter PV reads done (also orders Q staging)
#pragma unroll
        for (int u = 0; u < 2; ++u) {
            int slot = u * 256 + t;
            int row = slot >> 3;
            int e8 = (slot & 7) * 8;
            *(uint4*)&K_s[row * 72 + e8] =
                *(const uint4*)(Kg + (size_t)(b * SS + key0 + row) * SH + h * HD + e8);
            *(uint4*)&Vt_s[row * 72 + e8] =
                *(const uint4*)(Vtg + (size_t)(h * HD + row) * (SB * SS) + b * SS + key0 + e8);
        }
        __syncthreads();

        f32x4 s[2][4];
#pragma unroll
        for (int i = 0; i < 2; ++i)
#pragma unroll
            for (int j = 0; j < 4; ++j) s[i][j] = (f32x4){0.f, 0.f, 0.f, 0.f};
#pragma unroll
        for (int ki = 0; ki < 2; ++ki) {
            f16x8 ah[2];
#pragma unroll
            for (int i = 0; i < 2; ++i)
                ah[i] = *(const f16x8*)&Q_s[(wq + i * 16 + lrow) * 72 + ki * 32 + lk8];
#pragma unroll
            for (int j = 0; j < 4; ++j) {
                f16x8 bh = *(const f16x8*)&K_s[(j * 16 + lrow) * 72 + ki * 32 + lk8];
#pragma unroll
                for (int i = 0; i < 2; ++i)
                    s[i][j] = __builtin_amdgcn_mfma_f32_16x16x32_f16(ah[i], bh, s[i][j], 0, 0, 0);
            }
        }

        // mask + exp (fp32), row-sum partials, P -> bf16 LDS (A-layout rows).
        // Each wave writes/reads only its own P rows -> no barrier before PV.
#pragma unroll
        for (int i = 0; i < 2; ++i)
#pragma unroll
            for (int j = 0; j < 4; ++j) {
                int jg = key0 + j * 16 + lrow;
#pragma unroll
                for (int r = 0; r < 4; ++r) {
                    int qg = t0 + wq + i * 16 + rq + r;
                    float p = (jg <= qg && jg > qg - WIN) ? __expf(s[i][j][r]) : 0.f;
                    lsum[i][r] += p;
                    P_s[(wq + i * 16 + rq + r) * 72 + j * 16 + lrow] = pk1(p);
                }
            }

        // ctx += P @ V (bf16 MFMA, keys = reduction dim)
#pragma unroll
        for (int ki = 0; ki < 2; ++ki) {
            bf16x8 pf[2];
#pragma unroll
            for (int i = 0; i < 2; ++i)
                pf[i] = *(const bf16x8*)&P_s[(wq + i * 16 + lrow) * 72 + ki * 32 + lk8];
#pragma unroll
            for (int j = 0; j < 4; ++j) {
                bf16x8 vf = *(const bf16x8*)&Vt_s[(j * 16 + lrow) * 72 + ki * 32 + lk8];
#pragma unroll
                for (int i = 0; i < 2; ++i)
                    o[i][j] = __builtin_amdgcn_mfma_f32_16x16x32_bf16(pf[i], vf, o[i][j], 0, 0, 0);
            }
        }
    }

    // Row sums across the 16 lanes sharing each row.
#pragma unroll
    for (int i = 0; i < 2; ++i)
#pragma unroll
        for (int r = 0; r < 4; ++r) {
#pragma unroll
            for (int m = 1; m < 16; m <<= 1)
                lsum[i][r] += __shfl_xor(lsum[i][r], m);
        }

    // Normalize + ablation-mask -> f16 via LDS (reuse Q_s; wave owns its rows).
#pragma unroll
    for (int i = 0; i < 2; ++i)
#pragma unroll
        for (int r = 0; r < 4; ++r) {
            float inv = 1.f / lsum[i][r];
            int ql = wq + i * 16 + rq + r;
#pragma unroll
            for (int j = 0; j < 4; ++j) {
                int d = j * 16 + lrow;
                float msk = amask[(size_t)(b * SS + t0 + ql) * SH + h * HD + d];
                Q_s[ql * 72 + d] = (_Float16)(o[i][j][r] * inv * msk);
            }
        }
    __syncthreads();
#pragma unroll
    for (int u = 0; u < 4; ++u) {
        int slot = u * 256 + t;
        int row = slot >> 3;
        int d8 = (slot & 7) * 8;
        *(uint4*)(ctxg + (size_t)(b * SS + t0 + row) * SH + h * HD + d8) =
            *(const uint4*)&Q_s[row * 72 + d8];
    }
}

extern "C" void kernel_launch(void* const* d_in, const int* in_sizes, int n_in,
                              void* d_out, int out_size, void* d_ws, size_t ws_size,
                              hipStream_t stream)
{
    const float* x     = (const float*)d_in[0];
    const float* xc    = (const float*)d_in[1];
    const float* amask = (const float*)d_in[2];
    const float* Wq    = (const float*)d_in[3];
    const float* Wk    = (const float*)d_in[4];
    const float* Wv    = (const float*)d_in[5];
    const float* Wo    = (const float*)d_in[6];
    const float* bo    = (const float*)d_in[7];
    float* out = (float*)d_out;

    const int M = SB * SS;                       // 8192
    const size_t BUF = (size_t)M * SH;           // 8.4M elems (16MB @ 2B)
    const size_t WBUF = (size_t)SH * SH;         // 1M elems (2MB @ 2B)
    _Float16* xh  = (_Float16*)d_ws;             // 16MB
    _Float16* xch = xh + BUF;                    // 16MB
    _Float16* Qh  = xch + BUF;                   // 16MB (ctx aliases)
    _Float16* Kh  = Qh + BUF;                    // 16MB
    unsigned short* Vt = (unsigned short*)(Kh + BUF);   // 16MB bf16 V^T
    _Float16* Wqh = (_Float16*)(Vt + BUF);       // 4 x 2MB weights => 88MB total
    _Float16* Wkh = Wqh + WBUF;
    _Float16* Wvh = Wkh + WBUF;
    _Float16* Woh = Wvh + WBUF;
    _Float16* ctx = Qh;

    const int w4 = SH * SH / 4;
    const int i4 = M * SH / 4;
    hipLaunchKernelGGL(cvt_f16, dim3(i4 / 256), dim3(256), 0, stream, x,  xh,  i4);
    hipLaunchKernelGGL(cvt_f16, dim3(i4 / 256), dim3(256), 0, stream, xc, xch, i4);
    hipLaunchKernelGGL(cvt_f16, dim3(w4 / 256), dim3(256), 0, stream, Wq, Wqh, w4);
    hipLaunchKernelGGL(cvt_f16, dim3(w4 / 256), dim3(256), 0, stream, Wk, Wkh, w4);
    hipLaunchKernelGGL(cvt_f16, dim3(w4 / 256), dim3(256), 0, stream, Wv, Wvh, w4);
    hipLaunchKernelGGL(cvt_f16, dim3(w4 / 256), dim3(256), 0, stream, Wo, Woh, w4);

    dim3 gg(M / 128, SH / 128);
    dim3 gb(256);
    hipLaunchKernelGGL((gemm3<1>), gg, gb, 0, stream, xh,  Wqh, bo, (void*)Qh, M, SH, SH);
    hipLaunchKernelGGL((gemm3<1>), gg, gb, 0, stream, xch, Wkh, bo, (void*)Kh, M, SH, SH);
    hipLaunchKernelGGL((gemm3<2>), gg, gb, 0, stream, xch, Wvh, bo, (void*)Vt, M, SH, SH);

    hipLaunchKernelGGL(attn_mfma, dim3(SS / 128, NH, SB), dim3(256), 0, stream,
                       Qh, Kh, Vt, amask, ctx);

    hipLaunchKernelGGL((gemm3<0>), gg, gb, 0, stream, ctx, Woh, bo, (void*)out, M, SH, SH);
}

// Round 7
// 309.743 us; speedup vs baseline: 3.8957x; 1.0301x over previous
//
#include <hip/hip_runtime.h>
#include <hip/hip_bf16.h>
#include <cstddef>

#define SB 4
#define SS 2048
#define SH 1024
#define NH 16
#define HD 64
#define WIN 256

typedef __attribute__((ext_vector_type(8))) short bf16x8;
typedef __attribute__((ext_vector_type(8))) _Float16 f16x8;
typedef __attribute__((ext_vector_type(2))) __fp16 fp16v2;
typedef __attribute__((ext_vector_type(4))) float f32x4;

static __device__ __forceinline__ ushort2 pk_bf16(float a, float b) {
    __hip_bfloat162 h = __float22bfloat162_rn(make_float2(a, b));
    union { __hip_bfloat162 h2; ushort2 u2; } u;
    u.h2 = h;
    return u.u2;
}
static __device__ __forceinline__ unsigned short pk1(float a) {
    return pk_bf16(a, 0.f).x;
}

// Async global->LDS, 16B per lane. LDS dest is wave-uniform base + lane*16
// (m104/m108): pass the SAME lds pointer from every lane; layout must be
// contiguous in lane order.
static __device__ __forceinline__ void async16(const void* gptr, void* lptr) {
    __builtin_amdgcn_global_load_lds(
        (const __attribute__((address_space(1))) unsigned int*)gptr,
        (__attribute__((address_space(3))) unsigned int*)lptr, 16, 0, 0);
}

// All six fp32->f16 conversions in one launch. Segment sizes are powers of 2:
// x (2^21 float4), xc (2^21), then 4 weights (2^18 each).
__global__ __launch_bounds__(256) void cvt_all(
    const float* __restrict__ x,  const float* __restrict__ xc,
    const float* __restrict__ Wq, const float* __restrict__ Wk,
    const float* __restrict__ Wv, const float* __restrict__ Wo,
    _Float16* __restrict__ xh,  _Float16* __restrict__ xch,
    _Float16* __restrict__ Wqh, _Float16* __restrict__ Wkh,
    _Float16* __restrict__ Wvh, _Float16* __restrict__ Woh)
{
    const int I4 = SB * SS * SH / 4;       // 2^21
    const int W4 = SH * SH / 4;            // 2^18
    int idx = blockIdx.x * 256 + threadIdx.x;
    const float* src;
    _Float16* dst;
    int off;
    if (idx < I4) { src = x; dst = xh; off = idx; }
    else if (idx < 2 * I4) { src = xc; dst = xch; off = idx - I4; }
    else {
        int r = idx - 2 * I4;
        int wi = r >> 18;
        off = r & (W4 - 1);
        src = (wi == 0) ? Wq : (wi == 1) ? Wk : (wi == 2) ? Wv : Wo;
        dst = (wi == 0) ? Wqh : (wi == 1) ? Wkh : (wi == 2) ? Wvh : Woh;
    }
    float4 v = ((const float4*)src)[off];
    union { fp16v2 h[2]; uint2 u; } t;
    t.h[0] = __builtin_amdgcn_cvt_pkrtz(v.x, v.y);
    t.h[1] = __builtin_amdgcn_cvt_pkrtz(v.z, v.w);
    ((uint2*)dst)[off] = t.u;
}

// C[M,N] = A[M,K] @ W[N,K]^T, f16 operands, fp32 acc. m97 structure:
// 128x128 tile, BK=32, unpadded [row][32] LDS tiles, global_load_lds w=16.
// OUTM: 0 = fp32 + bias -> C1(float*)              [O]
//       1 = f16 -> C1(_Float16*)                   [Q,K]
//       2 = C^T[n][m] bf16 via LDS transpose -> C1 [V]
template<int OUTM>
__global__ __launch_bounds__(256) void gemm4(
    const _Float16* __restrict__ A, const _Float16* __restrict__ W,
    const float* __restrict__ bias, void* __restrict__ C1v,
    int M, int N, int K)
{
    __shared__ __align__(16) unsigned short smem[(OUTM == 2) ? 8704 : 8192];
    _Float16* Ah = (_Float16*)smem;          // [128][32] f16, 8KB
    _Float16* Bh = (_Float16*)smem + 4096;   // [128][32] f16, 8KB

    const int tid = threadIdx.x;
    const int m0 = blockIdx.x * 128;
    const int n0 = blockIdx.y * 128;
    const int wave = tid >> 6;
    const int lane = tid & 63;
    const int wm = (wave & 1) * 64;
    const int wn = (wave >> 1) * 64;
    const int lrow = lane & 15;
    const int lk8 = (lane >> 4) * 8;
    const int rq = (lane >> 4) * 4;

    f32x4 acc[4][4];
#pragma unroll
    for (int i = 0; i < 4; ++i)
#pragma unroll
        for (int j = 0; j < 4; ++j)
            acc[i][j] = (f32x4){0.f, 0.f, 0.f, 0.f};

    for (int k0 = 0; k0 < K; k0 += 32) {
        __syncthreads();
        // 8KB per tile = 8 wave-regions of 1KB; each (u,wave) stages one.
#pragma unroll
        for (int u = 0; u < 2; ++u) {
            int reg = u * 4 + wave;
            int slot = reg * 64 + lane;          // 4 lanes per 64B row
            int row = slot >> 2;
            int k8 = (slot & 3) * 8;
            async16(A + (size_t)(m0 + row) * K + k0 + k8, Ah + reg * 512);
            async16(W + (size_t)(n0 + row) * K + k0 + k8, Bh + reg * 512);
        }
        __syncthreads();

        f16x8 bf[4];
#pragma unroll
        for (int j = 0; j < 4; ++j)
            bf[j] = *(const f16x8*)&Bh[(wn + j * 16 + lrow) * 32 + lk8];
#pragma unroll
        for (int i = 0; i < 4; ++i) {
            f16x8 af = *(const f16x8*)&Ah[(wm + i * 16 + lrow) * 32 + lk8];
#pragma unroll
            for (int j = 0; j < 4; ++j)
                acc[i][j] = __builtin_amdgcn_mfma_f32_16x16x32_f16(af, bf[j], acc[i][j], 0, 0, 0);
        }
    }

    // C/D layout: col = lane&15, row = (lane>>4)*4 + reg.
    if (OUTM == 0) {
        float* C = (float*)C1v;
#pragma unroll
        for (int i = 0; i < 4; ++i) {
            int rbase = m0 + wm + i * 16 + rq;
#pragma unroll
            for (int j = 0; j < 4; ++j) {
                int col = n0 + wn + j * 16 + lrow;
                float badd = bias[col];
#pragma unroll
                for (int r = 0; r < 4; ++r)
                    C[(size_t)(rbase + r) * N + col] = acc[i][j][r] + badd;
            }
        }
    } else if (OUTM == 1) {
        _Float16* C = (_Float16*)C1v;
#pragma unroll
        for (int i = 0; i < 4; ++i) {
            int rbase = m0 + wm + i * 16 + rq;
#pragma unroll
            for (int j = 0; j < 4; ++j) {
                int col = n0 + wn + j * 16 + lrow;
#pragma unroll
                for (int r = 0; r < 4; ++r)
                    C[(size_t)(rbase + r) * N + col] = (_Float16)acc[i][j][r];
            }
        }
    } else {
        // Transposed bf16 out via LDS (pitch 136 shorts: 16B-aligned, 4-bank rot).
        unsigned short* Ct = (unsigned short*)C1v;   // C^T[n][m], row stride M
        unsigned short* T = smem;                    // 64 x 136 shorts = 17408B
#pragma unroll
        for (int p = 0; p < 2; ++p) {
            __syncthreads();
            if (wn == p * 64) {
#pragma unroll
                for (int i = 0; i < 4; ++i) {
                    int mloc = wm + i * 16 + rq;
#pragma unroll
                    for (int j = 0; j < 4; ++j) {
                        int cl = j * 16 + lrow;
                        *(ushort4*)&T[cl * 136 + mloc] = make_ushort4(
                            pk1(acc[i][j][0]), pk1(acc[i][j][1]),
                            pk1(acc[i][j][2]), pk1(acc[i][j][3]));
                    }
                }
            }
            __syncthreads();
#pragma unroll
            for (int u = 0; u < 4; ++u) {
                int slot = u * 256 + tid;
                int cl = slot >> 4;
                int m8 = (slot & 15) * 8;
                *(uint4*)(Ct + (size_t)(n0 + p * 64 + cl) * M + m0 + m8) =
                    *(const uint4*)&T[cl * 136 + m8];
            }
        }
    }
}

// MFMA flash attention, local causal window. Q A-fragments live in registers
// (wave only needs its own 32 rows); K/Vt staged async into unpadded
// [ki][64][32] halves; P round-trips LDS in bf16 (exp(s) up to ~e^47 needs
// bf16 range; no online max since fp32 can't overflow at |s|<~60).
// ctx may alias Qg: block reads exactly the rows it later writes, reads
// happen first, slices are block-exclusive -> race-free.
__global__ __launch_bounds__(256) void attn2(
    const _Float16* Qg, const _Float16* __restrict__ Kg,
    const unsigned short* __restrict__ Vtg, const float* __restrict__ amask,
    _Float16* ctxg)
{
    __shared__ __align__(16) _Float16 K_s[2 * 64 * 32];        // 8KB [ki][key][32d]
    __shared__ __align__(16) unsigned short Vt_s[2 * 64 * 32]; // 8KB [ki][d][32keys]
    __shared__ __align__(16) unsigned short P_s[128 * 72];     // 18KB bf16

    const int t = threadIdx.x;
    const int qb = blockIdx.x, h = blockIdx.y, b = blockIdx.z;
    const int t0 = qb * 128;
    const int wave = t >> 6, lane = t & 63;
    const int lrow = lane & 15;
    const int lk8 = (lane >> 4) * 8;
    const int wq = wave * 32;
    const int rq = (lane >> 4) * 4;
    const int M = SB * SS;

    // Q A-fragments in registers: wave's 32 rows, [i=row16-block][ki=k32-block]
    f16x8 qf[2][2];
#pragma unroll
    for (int i = 0; i < 2; ++i)
#pragma unroll
        for (int ki = 0; ki < 2; ++ki)
            qf[i][ki] = *(const f16x8*)(Qg +
                (size_t)(b * SS + t0 + wq + i * 16 + lrow) * SH + h * HD + ki * 32 + lk8);

    f32x4 o[2][4];
    float lsum[2][4];
#pragma unroll
    for (int i = 0; i < 2; ++i)
#pragma unroll
        for (int j = 0; j < 4; ++j) o[i][j] = (f32x4){0.f, 0.f, 0.f, 0.f};
#pragma unroll
    for (int i = 0; i < 2; ++i)
#pragma unroll
        for (int r = 0; r < 4; ++r) lsum[i][r] = 0.f;

    int cl = t0 - (WIN - 1);
    cl = cl < 0 ? 0 : cl;
    const int c_lo = cl >> 6;
    const int c_hi = (t0 >> 6) + 1;

    for (int c = c_lo; c <= c_hi; ++c) {
        const int key0 = c * 64;
        __syncthreads();   // prev-iter K/Vt/P reads complete
        // K half ki: [64 keys][32 d] = 4KB = 256 lanes x 16B. Same for Vt.
#pragma unroll
        for (int ki = 0; ki < 2; ++ki) {
            int slot = wave * 64 + lane;
            int row = slot >> 2;
            int e8 = (slot & 3) * 8;
            async16(Kg + (size_t)(b * SS + key0 + row) * SH + h * HD + ki * 32 + e8,
                    (_Float16*)K_s + ki * 2048 + wave * 512);
            async16(Vtg + (size_t)(h * HD + row) * M + b * SS + key0 + ki * 32 + e8,
                    (unsigned short*)Vt_s + ki * 2048 + wave * 512);
        }
        __syncthreads();

        // S = Q @ K^T
        f32x4 s[2][4];
#pragma unroll
        for (int i = 0; i < 2; ++i)
#pragma unroll
            for (int j = 0; j < 4; ++j) s[i][j] = (f32x4){0.f, 0.f, 0.f, 0.f};
#pragma unroll
        for (int ki = 0; ki < 2; ++ki) {
#pragma unroll
            for (int j = 0; j < 4; ++j) {
                f16x8 bh = *(const f16x8*)&K_s[ki * 2048 + (j * 16 + lrow) * 32 + lk8];
#pragma unroll
                for (int i = 0; i < 2; ++i)
                    s[i][j] = __builtin_amdgcn_mfma_f32_16x16x32_f16(qf[i][ki], bh, s[i][j], 0, 0, 0);
            }
        }

        // mask + exp (fp32), row-sum partials, P -> bf16 LDS (A-layout rows).
        // Each wave writes/reads only its own P rows -> no barrier before PV.
#pragma unroll
        for (int i = 0; i < 2; ++i)
#pragma unroll
            for (int j = 0; j < 4; ++j) {
                int jg = key0 + j * 16 + lrow;
#pragma unroll
                for (int r = 0; r < 4; ++r) {
                    int qg = t0 + wq + i * 16 + rq + r;
                    float p = (jg <= qg && jg > qg - WIN) ? __expf(s[i][j][r]) : 0.f;
                    lsum[i][r] += p;
                    P_s[(wq + i * 16 + rq + r) * 72 + j * 16 + lrow] = pk1(p);
                }
            }

        // ctx += P @ V  (keys = reduction dim)
#pragma unroll
        for (int ki = 0; ki < 2; ++ki) {
            bf16x8 pf[2];
#pragma unroll
            for (int i = 0; i < 2; ++i)
                pf[i] = *(const bf16x8*)&P_s[(wq + i * 16 + lrow) * 72 + ki * 32 + lk8];
#pragma unroll
            for (int j = 0; j < 4; ++j) {
                bf16x8 vf = *(const bf16x8*)&Vt_s[ki * 2048 + (j * 16 + lrow) * 32 + lk8];
#pragma unroll
                for (int i = 0; i < 2; ++i)
                    o[i][j] = __builtin_amdgcn_mfma_f32_16x16x32_bf16(pf[i], vf, o[i][j], 0, 0, 0);
            }
        }
    }

    // Row sums across the 16 lanes (4 xor steps stay within the quad group).
#pragma unroll
    for (int i = 0; i < 2; ++i)
#pragma unroll
        for (int r = 0; r < 4; ++r) {
#pragma unroll
            for (int m = 1; m < 16; m <<= 1)
                lsum[i][r] += __shfl_xor(lsum[i][r], m);
        }

    // Normalize + ablation mask, direct stores (quarter-wave-coalesced 32B).
#pragma unroll
    for (int i = 0; i < 2; ++i)
#pragma unroll
        for (int r = 0; r < 4; ++r) {
            float inv = 1.f / lsum[i][r];
            size_t rowb = (size_t)(b * SS + t0 + wq + i * 16 + rq + r) * SH + h * HD;
#pragma unroll
            for (int j = 0; j < 4; ++j) {
                int d = j * 16 + lrow;
                float msk = amask[rowb + d];
                ctxg[rowb + d] = (_Float16)(o[i][j][r] * inv * msk);
            }
        }
}

extern "C" void kernel_launch(void* const* d_in, const int* in_sizes, int n_in,
                              void* d_out, int out_size, void* d_ws, size_t ws_size,
                              hipStream_t stream)
{
    const float* x     = (const float*)d_in[0];
    const float* xc    = (const float*)d_in[1];
    const float* amask = (const float*)d_in[2];
    const float* Wq    = (const float*)d_in[3];
    const float* Wk    = (const float*)d_in[4];
    const float* Wv    = (const float*)d_in[5];
    const float* Wo    = (const float*)d_in[6];
    const float* bo    = (const float*)d_in[7];
    float* out = (float*)d_out;

    const int M = SB * SS;                       // 8192
    const size_t BUF = (size_t)M * SH;           // 8.4M elems (16MB @ 2B)
    const size_t WBUF = (size_t)SH * SH;         // 1M elems (2MB @ 2B)
    _Float16* xh  = (_Float16*)d_ws;             // 16MB
    _Float16* xch = xh + BUF;                    // 16MB
    _Float16* Qh  = xch + BUF;                   // 16MB (ctx aliases)
    _Float16* Kh  = Qh + BUF;                    // 16MB
    unsigned short* Vt = (unsigned short*)(Kh + BUF);   // 16MB bf16 V^T
    _Float16* Wqh = (_Float16*)(Vt + BUF);       // 4 x 2MB weights => 88MB total
    _Float16* Wkh = Wqh + WBUF;
    _Float16* Wvh = Wkh + WBUF;
    _Float16* Woh = Wvh + WBUF;
    _Float16* ctx = Qh;

    const int total4 = 2 * (M * SH / 4) + 4 * (SH * SH / 4);  // 5,242,880
    hipLaunchKernelGGL(cvt_all, dim3(total4 / 256), dim3(256), 0, stream,
                       x, xc, Wq, Wk, Wv, Wo, xh, xch, Wqh, Wkh, Wvh, Woh);

    dim3 gg(M / 128, SH / 128);
    dim3 gb(256);
    hipLaunchKernelGGL((gemm4<1>), gg, gb, 0, stream, xh,  Wqh, bo, (void*)Qh, M, SH, SH);
    hipLaunchKernelGGL((gemm4<1>), gg, gb, 0, stream, xch, Wkh, bo, (void*)Kh, M, SH, SH);
    hipLaunchKernelGGL((gemm4<2>), gg, gb, 0, stream, xch, Wvh, bo, (void*)Vt, M, SH, SH);

    hipLaunchKernelGGL(attn2, dim3(SS / 128, NH, SB), dim3(256), 0, stream,
                       Qh, Kh, Vt, amask, ctx);

    hipLaunchKernelGGL((gemm4<0>), gg, gb, 0, stream, ctx, Woh, bo, (void*)out, M, SH, SH);
}

// Round 8
// 304.401 us; speedup vs baseline: 3.9641x; 1.0175x over previous
//
#include <hip/hip_runtime.h>
#include <hip/hip_bf16.h>
#include <cstddef>

#define SB 4
#define SS 2048
#define SH 1024
#define NH 16
#define HD 64
#define WIN 256

typedef __attribute__((ext_vector_type(8))) short bf16x8;
typedef __attribute__((ext_vector_type(8))) _Float16 f16x8;
typedef __attribute__((ext_vector_type(2))) __fp16 fp16v2;
typedef __attribute__((ext_vector_type(4))) float f32x4;

static __device__ __forceinline__ ushort2 pk_bf16(float a, float b) {
    __hip_bfloat162 h = __float22bfloat162_rn(make_float2(a, b));
    union { __hip_bfloat162 h2; ushort2 u2; } u;
    u.h2 = h;
    return u.u2;
}
static __device__ __forceinline__ unsigned short pk1(float a) {
    return pk_bf16(a, 0.f).x;
}

// Async global->LDS, 16B per lane. LDS dest is wave-uniform base + lane*16
// (m104/m108): pass the SAME lds pointer from every lane; LDS layout must be
// contiguous in lane order.
static __device__ __forceinline__ void async16(const void* gptr, void* lptr) {
    __builtin_amdgcn_global_load_lds(
        (const __attribute__((address_space(1))) unsigned int*)gptr,
        (__attribute__((address_space(3))) unsigned int*)lptr, 16, 0, 0);
}

// All six fp32->f16 conversions in one launch. Segment sizes are powers of 2:
// x (2^21 float4), xc (2^21), then 4 weights (2^18 each).
__global__ __launch_bounds__(256) void cvt_all(
    const float* __restrict__ x,  const float* __restrict__ xc,
    const float* __restrict__ Wq, const float* __restrict__ Wk,
    const float* __restrict__ Wv, const float* __restrict__ Wo,
    _Float16* __restrict__ xh,  _Float16* __restrict__ xch,
    _Float16* __restrict__ Wqh, _Float16* __restrict__ Wkh,
    _Float16* __restrict__ Wvh, _Float16* __restrict__ Woh)
{
    const int I4 = SB * SS * SH / 4;       // 2^21
    const int W4 = SH * SH / 4;            // 2^18
    int idx = blockIdx.x * 256 + threadIdx.x;
    const float* src;
    _Float16* dst;
    int off;
    if (idx < I4) { src = x; dst = xh; off = idx; }
    else if (idx < 2 * I4) { src = xc; dst = xch; off = idx - I4; }
    else {
        int r = idx - 2 * I4;
        int wi = r >> 18;
        off = r & (W4 - 1);
        src = (wi == 0) ? Wq : (wi == 1) ? Wk : (wi == 2) ? Wv : Wo;
        dst = (wi == 0) ? Wqh : (wi == 1) ? Wkh : (wi == 2) ? Wvh : Woh;
    }
    float4 v = ((const float4*)src)[off];
    union { fp16v2 h[2]; uint2 u; } t;
    t.h[0] = __builtin_amdgcn_cvt_pkrtz(v.x, v.y);
    t.h[1] = __builtin_amdgcn_cvt_pkrtz(v.z, v.w);
    ((uint2*)dst)[off] = t.u;
}

// C[M,N] = A[M,K] @ W[N,K]^T, f16 operands, fp32 acc.
// 128x128 tile, BK=64 as two [ki][128][32] contiguous half-tiles:
// unpadded 64B rows (m97 bank pattern), async16 staging is 1KB fully
// coalesced per instruction, and barriers are halved vs BK=32.
// OUTM: 0 = fp32 + bias -> C1(float*)              [O]
//       1 = f16 -> C1(_Float16*)                   [Q,K]
//       2 = C^T[n][m] bf16 via LDS transpose -> C1 [V]
template<int OUTM>
__global__ __launch_bounds__(256) void gemm5(
    const _Float16* __restrict__ A, const _Float16* __restrict__ W,
    const float* __restrict__ bias, void* __restrict__ C1v,
    int M, int N, int K)
{
    __shared__ __align__(16) unsigned short smem[2 * 128 * 64]; // 32KB
    _Float16* Ah = (_Float16*)smem;          // [ki][128][32], 16KB
    _Float16* Bh = (_Float16*)smem + 8192;   // [ki][128][32], 16KB

    const int tid = threadIdx.x;
    const int m0 = blockIdx.x * 128;
    const int n0 = blockIdx.y * 128;
    const int wave = tid >> 6;
    const int lane = tid & 63;
    const int wm = (wave & 1) * 64;
    const int wn = (wave >> 1) * 64;
    const int lrow = lane & 15;
    const int lk8 = (lane >> 4) * 8;
    const int rq = (lane >> 4) * 4;

    f32x4 acc[4][4];
#pragma unroll
    for (int i = 0; i < 4; ++i)
#pragma unroll
        for (int j = 0; j < 4; ++j)
            acc[i][j] = (f32x4){0.f, 0.f, 0.f, 0.f};

    for (int k0 = 0; k0 < K; k0 += 64) {
        __syncthreads();
        // Per array: 2 halves x 8KB; 16 regions of 1KB; 4 per wave.
        // Region reg covers rows reg*4*... slot=reg*64+lane: row=slot>>2 within
        // half (4 lanes x 16B = 64B = one 32-f16 row), k8=(slot&3)*8.
#pragma unroll
        for (int ki = 0; ki < 2; ++ki)
#pragma unroll
            for (int u = 0; u < 2; ++u) {
                int reg = u * 4 + wave;            // 8 regions per half
                int slot = reg * 64 + lane;
                int row = slot >> 2;
                int k8 = (slot & 3) * 8;
                async16(A + (size_t)(m0 + row) * K + k0 + ki * 32 + k8,
                        Ah + ki * 4096 + reg * 512);
                async16(W + (size_t)(n0 + row) * K + k0 + ki * 32 + k8,
                        Bh + ki * 4096 + reg * 512);
            }
        __syncthreads();

#pragma unroll
        for (int ki = 0; ki < 2; ++ki) {
            f16x8 bf[4];
#pragma unroll
            for (int j = 0; j < 4; ++j)
                bf[j] = *(const f16x8*)&Bh[ki * 4096 + (wn + j * 16 + lrow) * 32 + lk8];
#pragma unroll
            for (int i = 0; i < 4; ++i) {
                f16x8 af = *(const f16x8*)&Ah[ki * 4096 + (wm + i * 16 + lrow) * 32 + lk8];
#pragma unroll
                for (int j = 0; j < 4; ++j)
                    acc[i][j] = __builtin_amdgcn_mfma_f32_16x16x32_f16(af, bf[j], acc[i][j], 0, 0, 0);
            }
        }
    }

    // C/D layout: col = lane&15, row = (lane>>4)*4 + reg.
    if (OUTM == 0) {
        float* C = (float*)C1v;
#pragma unroll
        for (int i = 0; i < 4; ++i) {
            int rbase = m0 + wm + i * 16 + rq;
#pragma unroll
            for (int j = 0; j < 4; ++j) {
                int col = n0 + wn + j * 16 + lrow;
                float badd = bias[col];
#pragma unroll
                for (int r = 0; r < 4; ++r)
                    C[(size_t)(rbase + r) * N + col] = acc[i][j][r] + badd;
            }
        }
    } else if (OUTM == 1) {
        _Float16* C = (_Float16*)C1v;
#pragma unroll
        for (int i = 0; i < 4; ++i) {
            int rbase = m0 + wm + i * 16 + rq;
#pragma unroll
            for (int j = 0; j < 4; ++j) {
                int col = n0 + wn + j * 16 + lrow;
#pragma unroll
                for (int r = 0; r < 4; ++r)
                    C[(size_t)(rbase + r) * N + col] = (_Float16)acc[i][j][r];
            }
        }
    } else {
        // Transposed bf16 out via LDS (pitch 136 shorts: 16B-aligned, 4-bank rot).
        unsigned short* Ct = (unsigned short*)C1v;   // C^T[n][m], row stride M
        unsigned short* T = smem;                    // 64 x 136 shorts = 17408B
#pragma unroll
        for (int p = 0; p < 2; ++p) {
            __syncthreads();
            if (wn == p * 64) {
#pragma unroll
                for (int i = 0; i < 4; ++i) {
                    int mloc = wm + i * 16 + rq;
#pragma unroll
                    for (int j = 0; j < 4; ++j) {
                        int cl = j * 16 + lrow;
                        *(ushort4*)&T[cl * 136 + mloc] = make_ushort4(
                            pk1(acc[i][j][0]), pk1(acc[i][j][1]),
                            pk1(acc[i][j][2]), pk1(acc[i][j][3]));
                    }
                }
            }
            __syncthreads();
#pragma unroll
            for (int u = 0; u < 4; ++u) {
                int slot = u * 256 + tid;
                int cl = slot >> 4;
                int m8 = (slot & 15) * 8;
                *(uint4*)(Ct + (size_t)(n0 + p * 64 + cl) * M + m0 + m8) =
                    *(const uint4*)&T[cl * 136 + m8];
            }
        }
    }
}

// Barrier-free MFMA flash attention. Each WAVE independently owns 32 queries:
// Q, K, V^T fragments are loaded straight from global into MFMA fragment
// layout (16B/lane), P round-trips a private LDS strip (in-wave dependency,
// compiler-inserted lgkmcnt only), epilogue transposes through the same strip
// for coalesced 16B stores. No __syncthreads anywhere; latency hiding comes
// from many independent waves per CU. P,V in bf16 (exp(s) up to ~e^47 needs
// bf16 range; fp32 can't overflow at |s|<~60, so no online max).
// ctx may alias Qg: each wave reads exactly the 32 Q rows it later writes,
// reads happen first, rows are wave-exclusive -> race-free.
__global__ __launch_bounds__(128) void attn3(
    const _Float16* Qg, const _Float16* __restrict__ Kg,
    const unsigned short* __restrict__ Vtg, const float* __restrict__ amask,
    _Float16* ctxg)
{
    __shared__ __align__(16) unsigned short P_s[2][32 * 72];   // 4.6KB per wave

    const int t = threadIdx.x;
    const int wave = t >> 6, lane = t & 63;
    const int h = blockIdx.y, b = blockIdx.z;
    const int wq = blockIdx.x * 64 + wave * 32;   // this wave's first query
    const int lrow = lane & 15;
    const int lk8 = (lane >> 4) * 8;              // quad*8
    const int rq = (lane >> 4) * 4;               // quad*4
    const int M = SB * SS;
    unsigned short* P = P_s[wave];

    // Q A-fragments (2 row-blocks x 2 k-halves), 16B/lane from global.
    f16x8 qf[2][2];
#pragma unroll
    for (int i = 0; i < 2; ++i)
#pragma unroll
        for (int ki = 0; ki < 2; ++ki)
            qf[i][ki] = *(const f16x8*)(Qg +
                (size_t)(b * SS + wq + i * 16 + lrow) * SH + h * HD + ki * 32 + lk8);

    f32x4 o[2][4];
    float lsum[2][4];
#pragma unroll
    for (int i = 0; i < 2; ++i)
#pragma unroll
        for (int j = 0; j < 4; ++j) o[i][j] = (f32x4){0.f, 0.f, 0.f, 0.f};
#pragma unroll
    for (int i = 0; i < 2; ++i)
#pragma unroll
        for (int r = 0; r < 4; ++r) lsum[i][r] = 0.f;

    int cl = wq - (WIN - 1);
    cl = cl < 0 ? 0 : cl;
    const int c_lo = cl >> 6;
    const int c_hi = (wq + 31) >> 6;

    for (int c = c_lo; c <= c_hi; ++c) {
        const int key0 = c * 64;

        // K B-fragments straight from global: lane holds K[key=lane&15+j*16][d=quad*8..]
        f16x8 kf[2][4];
#pragma unroll
        for (int ki = 0; ki < 2; ++ki)
#pragma unroll
            for (int j = 0; j < 4; ++j)
                kf[ki][j] = *(const f16x8*)(Kg +
                    (size_t)(b * SS + key0 + j * 16 + lrow) * SH + h * HD + ki * 32 + lk8);

        // S = Q @ K^T
        f32x4 s[2][4];
#pragma unroll
        for (int i = 0; i < 2; ++i)
#pragma unroll
            for (int j = 0; j < 4; ++j) s[i][j] = (f32x4){0.f, 0.f, 0.f, 0.f};
#pragma unroll
        for (int ki = 0; ki < 2; ++ki)
#pragma unroll
            for (int j = 0; j < 4; ++j)
#pragma unroll
                for (int i = 0; i < 2; ++i)
                    s[i][j] = __builtin_amdgcn_mfma_f32_16x16x32_f16(qf[i][ki], kf[ki][j], s[i][j], 0, 0, 0);

        // mask + exp (fp32), row-sum partials, P -> bf16 LDS (A-layout rows).
        // In-wave write->read dependency only.
#pragma unroll
        for (int i = 0; i < 2; ++i)
#pragma unroll
            for (int j = 0; j < 4; ++j) {
                int jg = key0 + j * 16 + lrow;
#pragma unroll
                for (int r = 0; r < 4; ++r) {
                    int qg = wq + i * 16 + rq + r;
                    float p = (jg <= qg && jg > qg - WIN) ? __expf(s[i][j][r]) : 0.f;
                    lsum[i][r] += p;
                    P[(i * 16 + rq + r) * 72 + j * 16 + lrow] = pk1(p);
                }
            }

        // V^T B-fragments straight from global: lane holds V^T[d=lane&15+j*16][key=quad*8..]
        bf16x8 vf[2][4];
#pragma unroll
        for (int ki = 0; ki < 2; ++ki)
#pragma unroll
            for (int j = 0; j < 4; ++j)
                vf[ki][j] = *(const bf16x8*)(Vtg +
                    (size_t)(h * HD + j * 16 + lrow) * M + b * SS + key0 + ki * 32 + lk8);

        // ctx += P @ V (keys = reduction dim)
#pragma unroll
        for (int ki = 0; ki < 2; ++ki) {
            bf16x8 pf[2];
#pragma unroll
            for (int i = 0; i < 2; ++i)
                pf[i] = *(const bf16x8*)&P[(i * 16 + lrow) * 72 + ki * 32 + lk8];
#pragma unroll
            for (int j = 0; j < 4; ++j)
#pragma unroll
                for (int i = 0; i < 2; ++i)
                    o[i][j] = __builtin_amdgcn_mfma_f32_16x16x32_bf16(pf[i], vf[ki][j], o[i][j], 0, 0, 0);
        }
    }

    // Row sums: the 16 lanes of a quad hold all 64 keys of a chunk for each
    // row -> 4 xor-shuffle steps within the quad group.
#pragma unroll
    for (int i = 0; i < 2; ++i)
#pragma unroll
        for (int r = 0; r < 4; ++r) {
#pragma unroll
            for (int m = 1; m < 16; m <<= 1)
                lsum[i][r] += __shfl_xor(lsum[i][r], m);
        }

    // Normalize into the LDS strip (f16), then read back row-contiguous,
    // apply ablation mask, 16B coalesced stores.
    _Float16* Pf = (_Float16*)P;
#pragma unroll
    for (int i = 0; i < 2; ++i)
#pragma unroll
        for (int r = 0; r < 4; ++r) {
            float inv = 1.f / lsum[i][r];
#pragma unroll
            for (int j = 0; j < 4; ++j)
                Pf[(i * 16 + rq + r) * 72 + j * 16 + lrow] = (_Float16)(o[i][j][r] * inv);
        }
#pragma unroll
    for (int u = 0; u < 4; ++u) {
        int slot = u * 64 + lane;
        int ro = slot >> 3;                 // local query row 0..31
        int d8 = (slot & 7) * 8;
        f16x8 v = *(const f16x8*)&Pf[ro * 72 + d8];
        size_t g = (size_t)(b * SS + wq + ro) * SH + h * HD + d8;
        float4 ma = *(const float4*)(amask + g);
        float4 mb = *(const float4*)(amask + g + 4);
        f16x8 rs;
        rs[0] = (_Float16)((float)v[0] * ma.x);
        rs[1] = (_Float16)((float)v[1] * ma.y);
        rs[2] = (_Float16)((float)v[2] * ma.z);
        rs[3] = (_Float16)((float)v[3] * ma.w);
        rs[4] = (_Float16)((float)v[4] * mb.x);
        rs[5] = (_Float16)((float)v[5] * mb.y);
        rs[6] = (_Float16)((float)v[6] * mb.z);
        rs[7] = (_Float16)((float)v[7] * mb.w);
        *(f16x8*)(ctxg + g) = rs;
    }
}

extern "C" void kernel_launch(void* const* d_in, const int* in_sizes, int n_in,
                              void* d_out, int out_size, void* d_ws, size_t ws_size,
                              hipStream_t stream)
{
    const float* x     = (const float*)d_in[0];
    const float* xc    = (const float*)d_in[1];
    const float* amask = (const float*)d_in[2];
    const float* Wq    = (const float*)d_in[3];
    const float* Wk    = (const float*)d_in[4];
    const float* Wv    = (const float*)d_in[5];
    const float* Wo    = (const float*)d_in[6];
    const float* bo    = (const float*)d_in[7];
    float* out = (float*)d_out;

    const int M = SB * SS;                       // 8192
    const size_t BUF = (size_t)M * SH;           // 8.4M elems (16MB @ 2B)
    const size_t WBUF = (size_t)SH * SH;         // 1M elems (2MB @ 2B)
    _Float16* xh  = (_Float16*)d_ws;             // 16MB
    _Float16* xch = xh + BUF;                    // 16MB
    _Float16* Qh  = xch + BUF;                   // 16MB (ctx aliases)
    _Float16* Kh  = Qh + BUF;                    // 16MB
    unsigned short* Vt = (unsigned short*)(Kh + BUF);   // 16MB bf16 V^T
    _Float16* Wqh = (_Float16*)(Vt + BUF);       // 4 x 2MB weights => 88MB total
    _Float16* Wkh = Wqh + WBUF;
    _Float16* Wvh = Wkh + WBUF;
    _Float16* Woh = Wvh + WBUF;
    _Float16* ctx = Qh;

    const int total4 = 2 * (M * SH / 4) + 4 * (SH * SH / 4);  // 5,242,880
    hipLaunchKernelGGL(cvt_all, dim3(total4 / 256), dim3(256), 0, stream,
                       x, xc, Wq, Wk, Wv, Wo, xh, xch, Wqh, Wkh, Wvh, Woh);

    dim3 gg(M / 128, SH / 128);
    dim3 gb(256);
    hipLaunchKernelGGL((gemm5<1>), gg, gb, 0, stream, xh,  Wqh, bo, (void*)Qh, M, SH, SH);
    hipLaunchKernelGGL((gemm5<1>), gg, gb, 0, stream, xch, Wkh, bo, (void*)Kh, M, SH, SH);
    hipLaunchKernelGGL((gemm5<2>), gg, gb, 0, stream, xch, Wvh, bo, (void*)Vt, M, SH, SH);

    hipLaunchKernelGGL(attn3, dim3(SS / 64, NH, SB), dim3(128), 0, stream,
                       Qh, Kh, Vt, amask, ctx);

    hipLaunchKernelGGL((gemm5<0>), gg, gb, 0, stream, ctx, Woh, bo, (void*)out, M, SH, SH);
}

// Round 9
// 288.615 us; speedup vs baseline: 4.1809x; 1.0547x over previous
//
#include <hip/hip_runtime.h>
#include <hip/hip_bf16.h>
#include <cstddef>

#define SB 4
#define SS 2048
#define SH 1024
#define NH 16
#define HD 64
#define WIN 256

typedef __attribute__((ext_vector_type(8))) short bf16x8;
typedef __attribute__((ext_vector_type(8))) _Float16 f16x8;
typedef __attribute__((ext_vector_type(2))) __fp16 fp16v2;
typedef __attribute__((ext_vector_type(4))) float f32x4;

static __device__ __forceinline__ ushort2 pk_bf16(float a, float b) {
    __hip_bfloat162 h = __float22bfloat162_rn(make_float2(a, b));
    union { __hip_bfloat162 h2; ushort2 u2; } u;
    u.h2 = h;
    return u.u2;
}
static __device__ __forceinline__ unsigned short pk1(float a) {
    return pk_bf16(a, 0.f).x;
}

// Async global->LDS, 16B per lane. LDS dest is wave-uniform base + lane*16
// (m104/m108): pass the SAME lds pointer from every lane.
static __device__ __forceinline__ void async16(const void* gptr, void* lptr) {
    __builtin_amdgcn_global_load_lds(
        (const __attribute__((address_space(1))) unsigned int*)gptr,
        (__attribute__((address_space(3))) unsigned int*)lptr, 16, 0, 0);
}

// All six fp32->f16 conversions in one launch.
__global__ __launch_bounds__(256) void cvt_all(
    const float* __restrict__ x,  const float* __restrict__ xc,
    const float* __restrict__ Wq, const float* __restrict__ Wk,
    const float* __restrict__ Wv, const float* __restrict__ Wo,
    _Float16* __restrict__ xh,  _Float16* __restrict__ xch,
    _Float16* __restrict__ Wqh, _Float16* __restrict__ Wkh,
    _Float16* __restrict__ Wvh, _Float16* __restrict__ Woh)
{
    const int I4 = SB * SS * SH / 4;       // 2^21
    const int W4 = SH * SH / 4;            // 2^18
    int idx = blockIdx.x * 256 + threadIdx.x;
    const float* src;
    _Float16* dst;
    int off;
    if (idx < I4) { src = x; dst = xh; off = idx; }
    else if (idx < 2 * I4) { src = xc; dst = xch; off = idx - I4; }
    else {
        int r = idx - 2 * I4;
        int wi = r >> 18;
        off = r & (W4 - 1);
        src = (wi == 0) ? Wq : (wi == 1) ? Wk : (wi == 2) ? Wv : Wo;
        dst = (wi == 0) ? Wqh : (wi == 1) ? Wkh : (wi == 2) ? Wvh : Woh;
    }
    float4 v = ((const float4*)src)[off];
    union { fp16v2 h[2]; uint2 u; } t;
    t.h[0] = __builtin_amdgcn_cvt_pkrtz(v.x, v.y);
    t.h[1] = __builtin_amdgcn_cvt_pkrtz(v.z, v.w);
    ((uint2*)dst)[off] = t.u;
}

// Fused Q/K/V projection GEMMs: blockIdx.z picks {A, W, epilogue}.
// C[M,N] = A[M,K] @ W[N,K]^T, f16 operands, fp32 acc, 128x128 tile, BK=64
// as two [ki][128][32] half-tiles (m97 64B-row bank pattern, async16 staging).
// z=0: x@Wq -> Qh (f16); z=1: xc@Wk -> Kh (f16); z=2: xc@Wv -> Vt (bf16, C^T).
__global__ __launch_bounds__(256) void gemm_qkv(
    const _Float16* __restrict__ xh, const _Float16* __restrict__ xch,
    const _Float16* __restrict__ Wqh, const _Float16* __restrict__ Wkh,
    const _Float16* __restrict__ Wvh,
    _Float16* __restrict__ Qh, _Float16* __restrict__ Kh,
    unsigned short* __restrict__ Vt)
{
    const int M = SB * SS, N = SH, K = SH;
    __shared__ __align__(16) unsigned short smem[2 * 128 * 64]; // 32KB
    _Float16* Ah = (_Float16*)smem;          // [ki][128][32], 16KB
    _Float16* Bh = (_Float16*)smem + 8192;   // [ki][128][32], 16KB

    const int z = blockIdx.z;
    const _Float16* A = (z == 0) ? xh : xch;
    const _Float16* W = (z == 0) ? Wqh : (z == 1) ? Wkh : Wvh;

    const int tid = threadIdx.x;
    const int m0 = blockIdx.x * 128;
    const int n0 = blockIdx.y * 128;
    const int wave = tid >> 6;
    const int lane = tid & 63;
    const int wm = (wave & 1) * 64;
    const int wn = (wave >> 1) * 64;
    const int lrow = lane & 15;
    const int lk8 = (lane >> 4) * 8;
    const int rq = (lane >> 4) * 4;

    f32x4 acc[4][4];
#pragma unroll
    for (int i = 0; i < 4; ++i)
#pragma unroll
        for (int j = 0; j < 4; ++j)
            acc[i][j] = (f32x4){0.f, 0.f, 0.f, 0.f};

    for (int k0 = 0; k0 < K; k0 += 64) {
        __syncthreads();
#pragma unroll
        for (int ki = 0; ki < 2; ++ki)
#pragma unroll
            for (int u = 0; u < 2; ++u) {
                int reg = u * 4 + wave;            // 8 regions of 1KB per half
                int slot = reg * 64 + lane;
                int row = slot >> 2;
                int k8 = (slot & 3) * 8;
                async16(A + (size_t)(m0 + row) * K + k0 + ki * 32 + k8,
                        Ah + ki * 4096 + reg * 512);
                async16(W + (size_t)(n0 + row) * K + k0 + ki * 32 + k8,
                        Bh + ki * 4096 + reg * 512);
            }
        __syncthreads();

#pragma unroll
        for (int ki = 0; ki < 2; ++ki) {
            f16x8 bf[4];
#pragma unroll
            for (int j = 0; j < 4; ++j)
                bf[j] = *(const f16x8*)&Bh[ki * 4096 + (wn + j * 16 + lrow) * 32 + lk8];
#pragma unroll
            for (int i = 0; i < 4; ++i) {
                f16x8 af = *(const f16x8*)&Ah[ki * 4096 + (wm + i * 16 + lrow) * 32 + lk8];
#pragma unroll
                for (int j = 0; j < 4; ++j)
                    acc[i][j] = __builtin_amdgcn_mfma_f32_16x16x32_f16(af, bf[j], acc[i][j], 0, 0, 0);
            }
        }
    }

    // C/D layout: col = lane&15, row = (lane>>4)*4 + reg.
    if (z < 2) {
        _Float16* C = (z == 0) ? Qh : Kh;
#pragma unroll
        for (int i = 0; i < 4; ++i) {
            int rbase = m0 + wm + i * 16 + rq;
#pragma unroll
            for (int j = 0; j < 4; ++j) {
                int col = n0 + wn + j * 16 + lrow;
#pragma unroll
                for (int r = 0; r < 4; ++r)
                    C[(size_t)(rbase + r) * N + col] = (_Float16)acc[i][j][r];
            }
        }
    } else {
        // Transposed bf16 out via LDS (pitch 136 shorts: 16B-aligned, 4-bank rot).
        unsigned short* T = smem;                    // 64 x 136 shorts
#pragma unroll
        for (int p = 0; p < 2; ++p) {
            __syncthreads();
            if (wn == p * 64) {
#pragma unroll
                for (int i = 0; i < 4; ++i) {
                    int mloc = wm + i * 16 + rq;
#pragma unroll
                    for (int j = 0; j < 4; ++j) {
                        int cl = j * 16 + lrow;
                        *(ushort4*)&T[cl * 136 + mloc] = make_ushort4(
                            pk1(acc[i][j][0]), pk1(acc[i][j][1]),
                            pk1(acc[i][j][2]), pk1(acc[i][j][3]));
                    }
                }
            }
            __syncthreads();
#pragma unroll
            for (int u = 0; u < 4; ++u) {
                int slot = u * 256 + tid;
                int cl = slot >> 4;
                int m8 = (slot & 15) * 8;
                *(uint4*)(Vt + (size_t)(n0 + p * 64 + cl) * M + m0 + m8) =
                    *(const uint4*)&T[cl * 136 + m8];
            }
        }
    }
}

// O-projection GEMM: ctx(f16) @ Wo^T + bo -> out (fp32).
__global__ __launch_bounds__(256) void gemm_o(
    const _Float16* __restrict__ A, const _Float16* __restrict__ W,
    const float* __restrict__ bias, float* __restrict__ C)
{
    const int M = SB * SS, N = SH, K = SH;
    __shared__ __align__(16) unsigned short smem[2 * 128 * 64]; // 32KB
    _Float16* Ah = (_Float16*)smem;
    _Float16* Bh = (_Float16*)smem + 8192;

    const int tid = threadIdx.x;
    const int m0 = blockIdx.x * 128;
    const int n0 = blockIdx.y * 128;
    const int wave = tid >> 6;
    const int lane = tid & 63;
    const int wm = (wave & 1) * 64;
    const int wn = (wave >> 1) * 64;
    const int lrow = lane & 15;
    const int lk8 = (lane >> 4) * 8;
    const int rq = (lane >> 4) * 4;

    f32x4 acc[4][4];
#pragma unroll
    for (int i = 0; i < 4; ++i)
#pragma unroll
        for (int j = 0; j < 4; ++j)
            acc[i][j] = (f32x4){0.f, 0.f, 0.f, 0.f};

    for (int k0 = 0; k0 < K; k0 += 64) {
        __syncthreads();
#pragma unroll
        for (int ki = 0; ki < 2; ++ki)
#pragma unroll
            for (int u = 0; u < 2; ++u) {
                int reg = u * 4 + wave;
                int slot = reg * 64 + lane;
                int row = slot >> 2;
                int k8 = (slot & 3) * 8;
                async16(A + (size_t)(m0 + row) * K + k0 + ki * 32 + k8,
                        Ah + ki * 4096 + reg * 512);
                async16(W + (size_t)(n0 + row) * K + k0 + ki * 32 + k8,
                        Bh + ki * 4096 + reg * 512);
            }
        __syncthreads();

#pragma unroll
        for (int ki = 0; ki < 2; ++ki) {
            f16x8 bf[4];
#pragma unroll
            for (int j = 0; j < 4; ++j)
                bf[j] = *(const f16x8*)&Bh[ki * 4096 + (wn + j * 16 + lrow) * 32 + lk8];
#pragma unroll
            for (int i = 0; i < 4; ++i) {
                f16x8 af = *(const f16x8*)&Ah[ki * 4096 + (wm + i * 16 + lrow) * 32 + lk8];
#pragma unroll
                for (int j = 0; j < 4; ++j)
                    acc[i][j] = __builtin_amdgcn_mfma_f32_16x16x32_f16(af, bf[j], acc[i][j], 0, 0, 0);
            }
        }
    }

#pragma unroll
    for (int i = 0; i < 4; ++i) {
        int rbase = m0 + wm + i * 16 + rq;
#pragma unroll
        for (int j = 0; j < 4; ++j) {
            int col = n0 + wn + j * 16 + lrow;
            float badd = bias[col];
#pragma unroll
            for (int r = 0; r < 4; ++r)
                C[(size_t)(rbase + r) * N + col] = acc[i][j][r] + badd;
        }
    }
}

// MFMA flash attention, local causal window, double-buffered K/V chunks.
// Block = 4 waves = 128 queries of one (b,h). Per iteration: issue async16
// staging of chunk c+1 into the OTHER buffer, compute chunk c (~500+ cyc of
// MFMA+exp), then barrier — the vmcnt drain at the barrier is cheap because
// the loads flew during compute. Waves skip chunks outside their own 287-key
// window (wave-uniform branch). P,V bf16 (exp(s) up to ~e^47 needs bf16
// range; no online max since fp32 can't overflow at |s|<~60).
// ctx may alias Qg: each wave reads exactly the 32 Q rows it later writes,
// reads happen before any write, rows are wave-exclusive -> race-free.
__global__ __launch_bounds__(256) void attn4(
    const _Float16* Qg, const _Float16* __restrict__ Kg,
    const unsigned short* __restrict__ Vtg, const float* __restrict__ amask,
    _Float16* ctxg)
{
    __shared__ __align__(16) _Float16 K_s[2][2 * 64 * 32];        // 16KB [buf][ki][key][32d]
    __shared__ __align__(16) unsigned short V_s[2][2 * 64 * 32];  // 16KB [buf][ki][d][32key]
    __shared__ __align__(16) unsigned short P_s[4][32 * 72];      // 18KB per-wave strips

    const int t = threadIdx.x;
    const int wave = t >> 6, lane = t & 63;
    const int qb = blockIdx.x, h = blockIdx.y, b = blockIdx.z;
    const int t0 = qb * 128;
    const int wq = t0 + wave * 32;               // this wave's first query
    const int lrow = lane & 15;
    const int lk8 = (lane >> 4) * 8;
    const int rq = (lane >> 4) * 4;
    const int M = SB * SS;
    unsigned short* P = P_s[wave];

    // Q A-fragments in registers (wave-private rows).
    f16x8 qf[2][2];
#pragma unroll
    for (int i = 0; i < 2; ++i)
#pragma unroll
        for (int ki = 0; ki < 2; ++ki)
            qf[i][ki] = *(const f16x8*)(Qg +
                (size_t)(b * SS + wq + i * 16 + lrow) * SH + h * HD + ki * 32 + lk8);

    f32x4 o[2][4];
    float lsum[2][4];
#pragma unroll
    for (int i = 0; i < 2; ++i)
#pragma unroll
        for (int j = 0; j < 4; ++j) o[i][j] = (f32x4){0.f, 0.f, 0.f, 0.f};
#pragma unroll
    for (int i = 0; i < 2; ++i)
#pragma unroll
        for (int r = 0; r < 4; ++r) lsum[i][r] = 0.f;

    int cl0 = t0 - (WIN - 1);
    cl0 = cl0 < 0 ? 0 : cl0;
    const int c_lo = cl0 >> 6;
    const int c_hi = (t0 >> 6) + 1;

    // Stage chunk c into buffer buf. 4KB per (array, ki-half): 256 lanes x 16B.
    auto stage = [&](int c, int buf) {
        const int key0 = c * 64;
#pragma unroll
        for (int ki = 0; ki < 2; ++ki) {
            int slot = wave * 64 + lane;
            int row = slot >> 2;
            int e8 = (slot & 3) * 8;
            async16(Kg + (size_t)(b * SS + key0 + row) * SH + h * HD + ki * 32 + e8,
                    (_Float16*)K_s[buf] + ki * 2048 + wave * 512);
            async16(Vtg + (size_t)(h * HD + row) * M + b * SS + key0 + ki * 32 + e8,
                    (unsigned short*)V_s[buf] + ki * 2048 + wave * 512);
        }
    };

    stage(c_lo, c_lo & 1);
    __syncthreads();

    for (int c = c_lo; c <= c_hi; ++c) {
        const int cur = c & 1;
        if (c < c_hi) stage(c + 1, cur ^ 1);     // overlaps the compute below
        const int key0 = c * 64;
        // Wave-uniform skip: does chunk intersect this wave's key window?
        if (key0 <= wq + 31 && key0 + 63 >= wq - (WIN - 1)) {
            const _Float16* Kc = (const _Float16*)K_s[cur];
            const unsigned short* Vc = (const unsigned short*)V_s[cur];

            // S = Q @ K^T
            f32x4 s[2][4];
#pragma unroll
            for (int i = 0; i < 2; ++i)
#pragma unroll
                for (int j = 0; j < 4; ++j) s[i][j] = (f32x4){0.f, 0.f, 0.f, 0.f};
#pragma unroll
            for (int ki = 0; ki < 2; ++ki)
#pragma unroll
                for (int j = 0; j < 4; ++j) {
                    f16x8 bh = *(const f16x8*)&Kc[ki * 2048 + (j * 16 + lrow) * 32 + lk8];
#pragma unroll
                    for (int i = 0; i < 2; ++i)
                        s[i][j] = __builtin_amdgcn_mfma_f32_16x16x32_f16(qf[i][ki], bh, s[i][j], 0, 0, 0);
                }

            // mask + exp (fp32), row-sum partials, P -> bf16 LDS (A-layout rows).
#pragma unroll
            for (int i = 0; i < 2; ++i)
#pragma unroll
                for (int j = 0; j < 4; ++j) {
                    int jg = key0 + j * 16 + lrow;
#pragma unroll
                    for (int r = 0; r < 4; ++r) {
                        int qg = wq + i * 16 + rq + r;
                        float p = (jg <= qg && jg > qg - WIN) ? __expf(s[i][j][r]) : 0.f;
                        lsum[i][r] += p;
                        P[(i * 16 + rq + r) * 72 + j * 16 + lrow] = pk1(p);
                    }
                }

            // ctx += P @ V (in-wave LDS dependency only)
#pragma unroll
            for (int ki = 0; ki < 2; ++ki) {
                bf16x8 pf[2];
#pragma unroll
                for (int i = 0; i < 2; ++i)
                    pf[i] = *(const bf16x8*)&P[(i * 16 + lrow) * 72 + ki * 32 + lk8];
#pragma unroll
                for (int j = 0; j < 4; ++j) {
                    bf16x8 vf = *(const bf16x8*)&Vc[ki * 2048 + (j * 16 + lrow) * 32 + lk8];
#pragma unroll
                    for (int i = 0; i < 2; ++i)
                        o[i][j] = __builtin_amdgcn_mfma_f32_16x16x32_bf16(pf[i], vf, o[i][j], 0, 0, 0);
                }
            }
        }
        __syncthreads();   // drains next-chunk staging (already in flight) + guards buffers
    }

    // Row sums: 4 xor-shuffle steps within the 16-lane row group.
#pragma unroll
    for (int i = 0; i < 2; ++i)
#pragma unroll
        for (int r = 0; r < 4; ++r) {
#pragma unroll
            for (int m = 1; m < 16; m <<= 1)
                lsum[i][r] += __shfl_xor(lsum[i][r], m);
        }

    // Normalize into the wave's strip (f16), read back row-contiguous,
    // apply ablation mask, 16B coalesced stores.
    _Float16* Pf = (_Float16*)P;
#pragma unroll
    for (int i = 0; i < 2; ++i)
#pragma unroll
        for (int r = 0; r < 4; ++r) {
            float inv = 1.f / lsum[i][r];
#pragma unroll
            for (int j = 0; j < 4; ++j)
                Pf[(i * 16 + rq + r) * 72 + j * 16 + lrow] = (_Float16)(o[i][j][r] * inv);
        }
#pragma unroll
    for (int u = 0; u < 4; ++u) {
        int slot = u * 64 + lane;
        int ro = slot >> 3;                 // local query row 0..31
        int d8 = (slot & 7) * 8;
        f16x8 v = *(const f16x8*)&Pf[ro * 72 + d8];
        size_t g = (size_t)(b * SS + wq + ro) * SH + h * HD + d8;
        float4 ma = *(const float4*)(amask + g);
        float4 mb = *(const float4*)(amask + g + 4);
        f16x8 rs;
        rs[0] = (_Float16)((float)v[0] * ma.x);
        rs[1] = (_Float16)((float)v[1] * ma.y);
        rs[2] = (_Float16)((float)v[2] * ma.z);
        rs[3] = (_Float16)((float)v[3] * ma.w);
        rs[4] = (_Float16)((float)v[4] * mb.x);
        rs[5] = (_Float16)((float)v[5] * mb.y);
        rs[6] = (_Float16)((float)v[6] * mb.z);
        rs[7] = (_Float16)((float)v[7] * mb.w);
        *(f16x8*)(ctxg + g) = rs;
    }
}

extern "C" void kernel_launch(void* const* d_in, const int* in_sizes, int n_in,
                              void* d_out, int out_size, void* d_ws, size_t ws_size,
                              hipStream_t stream)
{
    const float* x     = (const float*)d_in[0];
    const float* xc    = (const float*)d_in[1];
    const float* amask = (const float*)d_in[2];
    const float* Wq    = (const float*)d_in[3];
    const float* Wk    = (const float*)d_in[4];
    const float* Wv    = (const float*)d_in[5];
    const float* Wo    = (const float*)d_in[6];
    const float* bo    = (const float*)d_in[7];
    float* out = (float*)d_out;

    const int M = SB * SS;                       // 8192
    const size_t BUF = (size_t)M * SH;           // 8.4M elems (16MB @ 2B)
    const size_t WBUF = (size_t)SH * SH;         // 1M elems (2MB @ 2B)
    _Float16* xh  = (_Float16*)d_ws;             // 16MB
    _Float16* xch = xh + BUF;                    // 16MB
    _Float16* Qh  = xch + BUF;                   // 16MB (ctx aliases)
    _Float16* Kh  = Qh + BUF;                    // 16MB
    unsigned short* Vt = (unsigned short*)(Kh + BUF);   // 16MB bf16 V^T
    _Float16* Wqh = (_Float16*)(Vt + BUF);       // 4 x 2MB weights => 88MB total
    _Float16* Wkh = Wqh + WBUF;
    _Float16* Wvh = Wkh + WBUF;
    _Float16* Woh = Wvh + WBUF;
    _Float16* ctx = Qh;

    const int total4 = 2 * (M * SH / 4) + 4 * (SH * SH / 4);
    hipLaunchKernelGGL(cvt_all, dim3(total4 / 256), dim3(256), 0, stream,
                       x, xc, Wq, Wk, Wv, Wo, xh, xch, Wqh, Wkh, Wvh, Woh);

    hipLaunchKernelGGL(gemm_qkv, dim3(M / 128, SH / 128, 3), dim3(256), 0, stream,
                       xh, xch, Wqh, Wkh, Wvh, Qh, Kh, Vt);

    hipLaunchKernelGGL(attn4, dim3(SS / 128, NH, SB), dim3(256), 0, stream,
                       Qh, Kh, Vt, amask, ctx);

    hipLaunchKernelGGL(gemm_o, dim3(M / 128, SH / 128), dim3(256), 0, stream,
                       ctx, Woh, bo, out);
}

// Round 10
// 276.800 us; speedup vs baseline: 4.3593x; 1.0427x over previous
//
#include <hip/hip_runtime.h>
#include <hip/hip_bf16.h>
#include <cstddef>

#define SB 4
#define SS 2048
#define SH 1024
#define NH 16
#define HD 64
#define WIN 256

typedef __attribute__((ext_vector_type(8))) short bf16x8;
typedef __attribute__((ext_vector_type(8))) _Float16 f16x8;
typedef __attribute__((ext_vector_type(2))) __fp16 fp16v2;
typedef __attribute__((ext_vector_type(4))) float f32x4;

static __device__ __forceinline__ ushort2 pk_bf16(float a, float b) {
    __hip_bfloat162 h = __float22bfloat162_rn(make_float2(a, b));
    union { __hip_bfloat162 h2; ushort2 u2; } u;
    u.h2 = h;
    return u.u2;
}
static __device__ __forceinline__ unsigned short pk1(float a) {
    return pk_bf16(a, 0.f).x;
}

// Async global->LDS, 16B per lane. LDS dest is wave-uniform base + lane*16
// (m104/m108): pass the SAME lds pointer from every lane.
static __device__ __forceinline__ void async16(const void* gptr, void* lptr) {
    __builtin_amdgcn_global_load_lds(
        (const __attribute__((address_space(1))) unsigned int*)gptr,
        (__attribute__((address_space(3))) unsigned int*)lptr, 16, 0, 0);
}

// All six fp32->f16 conversions in one launch.
__global__ __launch_bounds__(256) void cvt_all(
    const float* __restrict__ x,  const float* __restrict__ xc,
    const float* __restrict__ Wq, const float* __restrict__ Wk,
    const float* __restrict__ Wv, const float* __restrict__ Wo,
    _Float16* __restrict__ xh,  _Float16* __restrict__ xch,
    _Float16* __restrict__ Wqh, _Float16* __restrict__ Wkh,
    _Float16* __restrict__ Wvh, _Float16* __restrict__ Woh)
{
    const int I4 = SB * SS * SH / 4;       // 2^21
    const int W4 = SH * SH / 4;            // 2^18
    int idx = blockIdx.x * 256 + threadIdx.x;
    const float* src;
    _Float16* dst;
    int off;
    if (idx < I4) { src = x; dst = xh; off = idx; }
    else if (idx < 2 * I4) { src = xc; dst = xch; off = idx - I4; }
    else {
        int r = idx - 2 * I4;
        int wi = r >> 18;
        off = r & (W4 - 1);
        src = (wi == 0) ? Wq : (wi == 1) ? Wk : (wi == 2) ? Wv : Wo;
        dst = (wi == 0) ? Wqh : (wi == 1) ? Wkh : (wi == 2) ? Wvh : Woh;
    }
    float4 v = ((const float4*)src)[off];
    union { fp16v2 h[2]; uint2 u; } t;
    t.h[0] = __builtin_amdgcn_cvt_pkrtz(v.x, v.y);
    t.h[1] = __builtin_amdgcn_cvt_pkrtz(v.z, v.w);
    ((uint2*)dst)[off] = t.u;
}

// Fused Q/K/V projection GEMMs: blockIdx.z picks {A, W, epilogue}.
// C[M,N] = A[M,K] @ W[N,K]^T, f16 operands, fp32 acc, 128x128 tile, BK=64
// as two [ki][128][32] half-tiles (m97 64B-row bank pattern, async16 staging).
// ALL epilogues now go through an LDS transpose for b128 coalesced stores
// (pitch 136 shorts: 16B-aligned rows, 4-bank rotation).
// z=0: x@Wq -> Qh (f16); z=1: xc@Wk -> Kh (f16); z=2: xc@Wv -> Vt (bf16, C^T).
__global__ __launch_bounds__(256) void gemm_qkv(
    const _Float16* __restrict__ xh, const _Float16* __restrict__ xch,
    const _Float16* __restrict__ Wqh, const _Float16* __restrict__ Wkh,
    const _Float16* __restrict__ Wvh,
    _Float16* __restrict__ Qh, _Float16* __restrict__ Kh,
    unsigned short* __restrict__ Vt)
{
    const int M = SB * SS, N = SH, K = SH;
    __shared__ __align__(16) unsigned short smem[128 * 136]; // 34KB (K-loop uses 32KB)
    _Float16* Ah = (_Float16*)smem;          // [ki][128][32], 16KB
    _Float16* Bh = (_Float16*)smem + 8192;   // [ki][128][32], 16KB

    const int z = blockIdx.z;
    const _Float16* A = (z == 0) ? xh : xch;
    const _Float16* W = (z == 0) ? Wqh : (z == 1) ? Wkh : Wvh;

    const int tid = threadIdx.x;
    const int m0 = blockIdx.x * 128;
    const int n0 = blockIdx.y * 128;
    const int wave = tid >> 6;
    const int lane = tid & 63;
    const int wm = (wave & 1) * 64;
    const int wn = (wave >> 1) * 64;
    const int lrow = lane & 15;
    const int lk8 = (lane >> 4) * 8;
    const int rq = (lane >> 4) * 4;

    f32x4 acc[4][4];
#pragma unroll
    for (int i = 0; i < 4; ++i)
#pragma unroll
        for (int j = 0; j < 4; ++j)
            acc[i][j] = (f32x4){0.f, 0.f, 0.f, 0.f};

    for (int k0 = 0; k0 < K; k0 += 64) {
        __syncthreads();
#pragma unroll
        for (int ki = 0; ki < 2; ++ki)
#pragma unroll
            for (int u = 0; u < 2; ++u) {
                int reg = u * 4 + wave;            // 8 regions of 1KB per half
                int slot = reg * 64 + lane;
                int row = slot >> 2;
                int k8 = (slot & 3) * 8;
                async16(A + (size_t)(m0 + row) * K + k0 + ki * 32 + k8,
                        Ah + ki * 4096 + reg * 512);
                async16(W + (size_t)(n0 + row) * K + k0 + ki * 32 + k8,
                        Bh + ki * 4096 + reg * 512);
            }
        __syncthreads();

#pragma unroll
        for (int ki = 0; ki < 2; ++ki) {
            f16x8 bf[4];
#pragma unroll
            for (int j = 0; j < 4; ++j)
                bf[j] = *(const f16x8*)&Bh[ki * 4096 + (wn + j * 16 + lrow) * 32 + lk8];
#pragma unroll
            for (int i = 0; i < 4; ++i) {
                f16x8 af = *(const f16x8*)&Ah[ki * 4096 + (wm + i * 16 + lrow) * 32 + lk8];
#pragma unroll
                for (int j = 0; j < 4; ++j)
                    acc[i][j] = __builtin_amdgcn_mfma_f32_16x16x32_f16(af, bf[j], acc[i][j], 0, 0, 0);
            }
        }
    }

    // C/D layout: col = lane&15, row = (lane>>4)*4 + reg.
    if (z < 2) {
        // f16 out via full-tile LDS transpose -> b128 coalesced stores.
        _Float16* C = (z == 0) ? Qh : Kh;
        _Float16* T = (_Float16*)smem;           // 128 x 136 f16 = 34KB
        __syncthreads();                         // K-loop LDS reads done
#pragma unroll
        for (int i = 0; i < 4; ++i) {
            int rloc = wm + i * 16 + rq;
#pragma unroll
            for (int j = 0; j < 4; ++j) {
                int cl = wn + j * 16 + lrow;
#pragma unroll
                for (int r = 0; r < 4; ++r)
                    T[(rloc + r) * 136 + cl] = (_Float16)acc[i][j][r];
            }
        }
        __syncthreads();
#pragma unroll
        for (int u = 0; u < 8; ++u) {
            int slot = u * 256 + tid;            // 2048 uint4 slots
            int row = slot >> 4;
            int c8 = (slot & 15) * 8;
            *(uint4*)(C + (size_t)(m0 + row) * N + n0 + c8) =
                *(const uint4*)&T[row * 136 + c8];
        }
    } else {
        // Transposed bf16 out via LDS (64 x 136 shorts per pass).
        unsigned short* T = smem;
#pragma unroll
        for (int p = 0; p < 2; ++p) {
            __syncthreads();
            if (wn == p * 64) {
#pragma unroll
                for (int i = 0; i < 4; ++i) {
                    int mloc = wm + i * 16 + rq;
#pragma unroll
                    for (int j = 0; j < 4; ++j) {
                        int cl = j * 16 + lrow;
                        *(ushort4*)&T[cl * 136 + mloc] = make_ushort4(
                            pk1(acc[i][j][0]), pk1(acc[i][j][1]),
                            pk1(acc[i][j][2]), pk1(acc[i][j][3]));
                    }
                }
            }
            __syncthreads();
#pragma unroll
            for (int u = 0; u < 4; ++u) {
                int slot = u * 256 + tid;
                int cl = slot >> 4;
                int m8 = (slot & 15) * 8;
                *(uint4*)(Vt + (size_t)(n0 + p * 64 + cl) * M + m0 + m8) =
                    *(const uint4*)&T[cl * 136 + m8];
            }
        }
    }
}

// O-projection GEMM: ctx(f16) @ Wo^T + bo -> out (fp32).
__global__ __launch_bounds__(256) void gemm_o(
    const _Float16* __restrict__ A, const _Float16* __restrict__ W,
    const float* __restrict__ bias, float* __restrict__ C)
{
    const int M = SB * SS, N = SH, K = SH;
    __shared__ __align__(16) unsigned short smem[2 * 128 * 64]; // 32KB
    _Float16* Ah = (_Float16*)smem;
    _Float16* Bh = (_Float16*)smem + 8192;

    const int tid = threadIdx.x;
    const int m0 = blockIdx.x * 128;
    const int n0 = blockIdx.y * 128;
    const int wave = tid >> 6;
    const int lane = tid & 63;
    const int wm = (wave & 1) * 64;
    const int wn = (wave >> 1) * 64;
    const int lrow = lane & 15;
    const int lk8 = (lane >> 4) * 8;
    const int rq = (lane >> 4) * 4;

    f32x4 acc[4][4];
#pragma unroll
    for (int i = 0; i < 4; ++i)
#pragma unroll
        for (int j = 0; j < 4; ++j)
            acc[i][j] = (f32x4){0.f, 0.f, 0.f, 0.f};

    for (int k0 = 0; k0 < K; k0 += 64) {
        __syncthreads();
#pragma unroll
        for (int ki = 0; ki < 2; ++ki)
#pragma unroll
            for (int u = 0; u < 2; ++u) {
                int reg = u * 4 + wave;
                int slot = reg * 64 + lane;
                int row = slot >> 2;
                int k8 = (slot & 3) * 8;
                async16(A + (size_t)(m0 + row) * K + k0 + ki * 32 + k8,
                        Ah + ki * 4096 + reg * 512);
                async16(W + (size_t)(n0 + row) * K + k0 + ki * 32 + k8,
                        Bh + ki * 4096 + reg * 512);
            }
        __syncthreads();

#pragma unroll
        for (int ki = 0; ki < 2; ++ki) {
            f16x8 bf[4];
#pragma unroll
            for (int j = 0; j < 4; ++j)
                bf[j] = *(const f16x8*)&Bh[ki * 4096 + (wn + j * 16 + lrow) * 32 + lk8];
#pragma unroll
            for (int i = 0; i < 4; ++i) {
                f16x8 af = *(const f16x8*)&Ah[ki * 4096 + (wm + i * 16 + lrow) * 32 + lk8];
#pragma unroll
                for (int j = 0; j < 4; ++j)
                    acc[i][j] = __builtin_amdgcn_mfma_f32_16x16x32_f16(af, bf[j], acc[i][j], 0, 0, 0);
            }
        }
    }

#pragma unroll
    for (int i = 0; i < 4; ++i) {
        int rbase = m0 + wm + i * 16 + rq;
#pragma unroll
        for (int j = 0; j < 4; ++j) {
            int col = n0 + wn + j * 16 + lrow;
            float badd = bias[col];
#pragma unroll
            for (int r = 0; r < 4; ++r)
                C[(size_t)(rbase + r) * N + col] = acc[i][j][r] + badd;
        }
    }
}

// MFMA flash attention, local causal window. Block = 8 waves = 256 queries of
// one (b,h): halves barriers and K/V staging per query vs 128-query blocks.
// Double-buffered K/V chunks (stage c+1 during compute of c); waves skip
// chunks outside their 287-key window (wave-uniform branch). 1-D grid with
// id%8 == (h,b)-pair%8 so all qb-blocks of one (b,h) share one XCD's L2
// (K+V per pair = 512KB; 8 pairs/XCD = 4MB = L2 size). P,V bf16 (exp(s) up
// to ~e^47 needs bf16 range; no online max since fp32 can't overflow).
// ctx may alias Qg: each wave reads exactly the 32 Q rows it later writes,
// reads happen before any write, rows are wave-exclusive -> race-free.
__global__ __launch_bounds__(512, 4) void attn5(
    const _Float16* Qg, const _Float16* __restrict__ Kg,
    const unsigned short* __restrict__ Vtg, const float* __restrict__ amask,
    _Float16* ctxg)
{
    __shared__ __align__(16) _Float16 K_s[2][2 * 64 * 32];        // 16KB [buf][ki][key][32d]
    __shared__ __align__(16) unsigned short V_s[2][2 * 64 * 32];  // 16KB [buf][ki][d][32key]
    __shared__ __align__(16) unsigned short P_s[8][32 * 72];      // 36.9KB per-wave strips

    const int t = threadIdx.x;
    const int wave = t >> 6, lane = t & 63;
    const int id = blockIdx.x;        // 512 blocks
    const int qb = id >> 6;           // 0..7
    const int pr = id & 63;           // (h,b) pair; id%8 = pr%8 -> XCD grouping
    const int h = pr & 15, b = pr >> 4;
    const int t0 = qb * 256;
    const int wq = t0 + wave * 32;    // this wave's first query
    const int lrow = lane & 15;
    const int lk8 = (lane >> 4) * 8;
    const int rq = (lane >> 4) * 4;
    const int M = SB * SS;
    unsigned short* P = P_s[wave];

    // Staging decomposition: 512 threads x 16B = one full 8KB chunk per array.
    const int ski = t >> 8;           // ki half
    const int srow = (t & 255) >> 2;  // key row (K) / d row (Vt)
    const int se8 = (t & 3) * 8;

    // Q A-fragments in registers (wave-private rows).
    f16x8 qf[2][2];
#pragma unroll
    for (int i = 0; i < 2; ++i)
#pragma unroll
        for (int ki = 0; ki < 2; ++ki)
            qf[i][ki] = *(const f16x8*)(Qg +
                (size_t)(b * SS + wq + i * 16 + lrow) * SH + h * HD + ki * 32 + lk8);

    f32x4 o[2][4];
    float lsum[2][4];
#pragma unroll
    for (int i = 0; i < 2; ++i)
#pragma unroll
        for (int j = 0; j < 4; ++j) o[i][j] = (f32x4){0.f, 0.f, 0.f, 0.f};
#pragma unroll
    for (int i = 0; i < 2; ++i)
#pragma unroll
        for (int r = 0; r < 4; ++r) lsum[i][r] = 0.f;

    int cl0 = t0 - (WIN - 1);
    cl0 = cl0 < 0 ? 0 : cl0;
    const int c_lo = cl0 >> 6;
    const int c_hi = (t0 >> 6) + 3;   // keys up to t0+255

    auto stage = [&](int c, int buf) {
        const int key0 = c * 64;
        async16(Kg + (size_t)(b * SS + key0 + srow) * SH + h * HD + ski * 32 + se8,
                (_Float16*)K_s[buf] + wave * 512);
        async16(Vtg + (size_t)(h * HD + srow) * M + b * SS + key0 + ski * 32 + se8,
                (unsigned short*)V_s[buf] + wave * 512);
    };

    stage(c_lo, c_lo & 1);
    __syncthreads();

    for (int c = c_lo; c <= c_hi; ++c) {
        const int cur = c & 1;
        if (c < c_hi) stage(c + 1, cur ^ 1);     // flies during compute below
        const int key0 = c * 64;
        // Wave-uniform skip: does chunk intersect this wave's key window?
        if (key0 <= wq + 31 && key0 + 63 >= wq - (WIN - 1)) {
            const _Float16* Kc = (const _Float16*)K_s[cur];
            const unsigned short* Vc = (const unsigned short*)V_s[cur];

            // S = Q @ K^T
            f32x4 s[2][4];
#pragma unroll
            for (int i = 0; i < 2; ++i)
#pragma unroll
                for (int j = 0; j < 4; ++j) s[i][j] = (f32x4){0.f, 0.f, 0.f, 0.f};
#pragma unroll
            for (int ki = 0; ki < 2; ++ki)
#pragma unroll
                for (int j = 0; j < 4; ++j) {
                    f16x8 bh = *(const f16x8*)&Kc[ki * 2048 + (j * 16 + lrow) * 32 + lk8];
#pragma unroll
                    for (int i = 0; i < 2; ++i)
                        s[i][j] = __builtin_amdgcn_mfma_f32_16x16x32_f16(qf[i][ki], bh, s[i][j], 0, 0, 0);
                }

            // mask + exp (fp32), row-sum partials, P -> bf16 LDS (A-layout rows).
#pragma unroll
            for (int i = 0; i < 2; ++i)
#pragma unroll
                for (int j = 0; j < 4; ++j) {
                    int jg = key0 + j * 16 + lrow;
#pragma unroll
                    for (int r = 0; r < 4; ++r) {
                        int qg = wq + i * 16 + rq + r;
                        float p = (jg <= qg && jg > qg - WIN) ? __expf(s[i][j][r]) : 0.f;
                        lsum[i][r] += p;
                        P[(i * 16 + rq + r) * 72 + j * 16 + lrow] = pk1(p);
                    }
                }

            // ctx += P @ V (in-wave LDS dependency only)
#pragma unroll
            for (int ki = 0; ki < 2; ++ki) {
                bf16x8 pf[2];
#pragma unroll
                for (int i = 0; i < 2; ++i)
                    pf[i] = *(const bf16x8*)&P[(i * 16 + lrow) * 72 + ki * 32 + lk8];
#pragma unroll
                for (int j = 0; j < 4; ++j) {
                    bf16x8 vf = *(const bf16x8*)&Vc[ki * 2048 + (j * 16 + lrow) * 32 + lk8];
#pragma unroll
                    for (int i = 0; i < 2; ++i)
                        o[i][j] = __builtin_amdgcn_mfma_f32_16x16x32_bf16(pf[i], vf, o[i][j], 0, 0, 0);
                }
            }
        }
        __syncthreads();   // guards buffers; drains in-flight staging
    }

    // Row sums: 4 xor-shuffle steps within the 16-lane row group.
#pragma unroll
    for (int i = 0; i < 2; ++i)
#pragma unroll
        for (int r = 0; r < 4; ++r) {
#pragma unroll
            for (int m = 1; m < 16; m <<= 1)
                lsum[i][r] += __shfl_xor(lsum[i][r], m);
        }

    // Normalize into the wave's strip (f16), read back row-contiguous,
    // apply ablation mask, 16B coalesced stores.
    _Float16* Pf = (_Float16*)P;
#pragma unroll
    for (int i = 0; i < 2; ++i)
#pragma unroll
        for (int r = 0; r < 4; ++r) {
            float inv = 1.f / lsum[i][r];
#pragma unroll
            for (int j = 0; j < 4; ++j)
                Pf[(i * 16 + rq + r) * 72 + j * 16 + lrow] = (_Float16)(o[i][j][r] * inv);
        }
#pragma unroll
    for (int u = 0; u < 4; ++u) {
        int slot = u * 64 + lane;
        int ro = slot >> 3;                 // local query row 0..31
        int d8 = (slot & 7) * 8;
        f16x8 v = *(const f16x8*)&Pf[ro * 72 + d8];
        size_t g = (size_t)(b * SS + wq + ro) * SH + h * HD + d8;
        float4 ma = *(const float4*)(amask + g);
        float4 mb = *(const float4*)(amask + g + 4);
        f16x8 rs;
        rs[0] = (_Float16)((float)v[0] * ma.x);
        rs[1] = (_Float16)((float)v[1] * ma.y);
        rs[2] = (_Float16)((float)v[2] * ma.z);
        rs[3] = (_Float16)((float)v[3] * ma.w);
        rs[4] = (_Float16)((float)v[4] * mb.x);
        rs[5] = (_Float16)((float)v[5] * mb.y);
        rs[6] = (_Float16)((float)v[6] * mb.z);
        rs[7] = (_Float16)((float)v[7] * mb.w);
        *(f16x8*)(ctxg + g) = rs;
    }
}

extern "C" void kernel_launch(void* const* d_in, const int* in_sizes, int n_in,
                              void* d_out, int out_size, void* d_ws, size_t ws_size,
                              hipStream_t stream)
{
    const float* x     = (const float*)d_in[0];
    const float* xc    = (const float*)d_in[1];
    const float* amask = (const float*)d_in[2];
    const float* Wq    = (const float*)d_in[3];
    const float* Wk    = (const float*)d_in[4];
    const float* Wv    = (const float*)d_in[5];
    const float* Wo    = (const float*)d_in[6];
    const float* bo    = (const float*)d_in[7];
    float* out = (float*)d_out;

    const int M = SB * SS;                       // 8192
    const size_t BUF = (size_t)M * SH;           // 8.4M elems (16MB @ 2B)
    const size_t WBUF = (size_t)SH * SH;         // 1M elems (2MB @ 2B)
    _Float16* xh  = (_Float16*)d_ws;             // 16MB
    _Float16* xch = xh + BUF;                    // 16MB
    _Float16* Qh  = xch + BUF;                   // 16MB (ctx aliases)
    _Float16* Kh  = Qh + BUF;                    // 16MB
    unsigned short* Vt = (unsigned short*)(Kh + BUF);   // 16MB bf16 V^T
    _Float16* Wqh = (_Float16*)(Vt + BUF);       // 4 x 2MB weights => 88MB total
    _Float16* Wkh = Wqh + WBUF;
    _Float16* Wvh = Wkh + WBUF;
    _Float16* Woh = Wvh + WBUF;
    _Float16* ctx = Qh;

    const int total4 = 2 * (M * SH / 4) + 4 * (SH * SH / 4);
    hipLaunchKernelGGL(cvt_all, dim3(total4 / 256), dim3(256), 0, stream,
                       x, xc, Wq, Wk, Wv, Wo, xh, xch, Wqh, Wkh, Wvh, Woh);

    hipLaunchKernelGGL(gemm_qkv, dim3(M / 128, SH / 128, 3), dim3(256), 0, stream,
                       xh, xch, Wqh, Wkh, Wvh, Qh, Kh, Vt);

    hipLaunchKernelGGL(attn5, dim3((SS / 256) * NH * SB), dim3(512), 0, stream,
                       Qh, Kh, Vt, amask, ctx);

    hipLaunchKernelGGL(gemm_o, dim3(M / 128, SH / 128), dim3(256), 0, stream,
                       ctx, Woh, bo, out);
}